// Round 1
// baseline (10294.399 us; speedup 1.0000x reference)
//
#include <hip/hip_runtime.h>
#include <math.h>

#define NB 65536

// ws layout (float element offsets)
#define OFF_TAB2  0         // 16*101*96 = 155136
#define OFF_BIAST 155136    // 7*96
#define OFF_FC1P  155808    // 192*192
#define OFF_FC1C  192672    // 192
#define OFF_FC1B  192864    // 192
#define OFF_SP1P  193056    // 64*128
#define OFF_SPC   201248    // 128
#define OFF_SPB   201376    // 128
#define OFF_HM1P  201504    // 352*192
#define OFF_HMC   269088    // 192
#define OFF_HMB   269280    // 192
#define OFF_HQ1P  269472    // 352*192
#define OFF_HQC   337056    // 192
#define OFF_HQB   337248    // 192
#define OFF_HN1P  337440    // 352*96
#define OFF_HNC   371232    // 96
#define OFF_HNB   371328    // 96
#define OFF_FEAT  371424    // bf16 feat: 65536*288 ushorts after this float offset

__device__ __forceinline__ unsigned short f2b(float x) {
  unsigned int u = __float_as_uint(x);
  u += 0x7fffu + ((u >> 16) & 1u);   // round-to-nearest-even bf16
  return (unsigned short)(u >> 16);
}
__device__ __forceinline__ float geluf(float x) {
  return 0.5f * x * (1.0f + erff(x * 0.70710678118654752f));
}

// ---------------- K0: precompute folded tables into ws ----------------
__global__ void k0_pre(
    const float* __restrict__ cat_emb, const float* __restrict__ day_emb,
    const float* __restrict__ xproj_w, const float* __restrict__ xproj_b,
    const float* __restrict__ bln_g,  const float* __restrict__ bln_b,
    const float* __restrict__ fc1_w,  const float* __restrict__ fc1_b,
    const float* __restrict__ spln_g, const float* __restrict__ spln_b,
    const float* __restrict__ sp1_w,  const float* __restrict__ sp1_b,
    const float* __restrict__ hln_g,  const float* __restrict__ hln_b,
    const float* __restrict__ hm1_w,  const float* __restrict__ hm1_b,
    const float* __restrict__ hq1_w,  const float* __restrict__ hq1_b,
    const float* __restrict__ hn1_w,  const float* __restrict__ hn1_b,
    float* __restrict__ ws)
{
  const int bid = blockIdx.x, tid = threadIdx.x;  // 96 threads
  if (bid < 1616) {                       // tab2: project embedding rows
    const int c = bid / 101, idx = bid - c * 101;
    const int j = tid;
    float acc = 0.f;
    #pragma unroll
    for (int k = 0; k < 16; ++k)
      acc = fmaf(cat_emb[(c*101 + idx)*16 + k], xproj_w[(32 + c*16 + k)*96 + j], acc);
    ws[OFF_TAB2 + (c*101 + idx)*96 + j] = acc;
  } else if (bid < 1623) {                // per-t bias: xproj_b + day part
    const int t = bid - 1616, j = tid;
    float acc = xproj_b[j];
    #pragma unroll
    for (int d = 0; d < 8; ++d)
      acc = fmaf(day_emb[(1 + t)*8 + d], xproj_w[(288 + d)*96 + j], acc);
    ws[OFF_BIAST + t*96 + j] = acc;
  } else if (bid < 1625) {                // fc1 LN-fold
    const int j = (bid - 1623)*96 + tid;
    float C = 0.f, bp = fc1_b[j];
    for (int k = 0; k < 192; ++k) {
      const float wv = fc1_w[k*192 + j];
      const float wp = bln_g[k] * wv;
      ws[OFF_FC1P + k*192 + j] = wp;
      C += wp; bp = fmaf(bln_b[k], wv, bp);
    }
    ws[OFF_FC1C + j] = C; ws[OFF_FC1B + j] = bp;
  } else if (bid < 1627) {                // sp1 LN-fold (128 cols)
    const int j = (bid - 1625)*96 + tid;
    if (j < 128) {
      float C = 0.f, bp = sp1_b[j];
      for (int k = 0; k < 64; ++k) {
        const float wv = sp1_w[k*128 + j];
        const float wp = spln_g[k] * wv;
        ws[OFF_SP1P + k*128 + j] = wp;
        C += wp; bp = fmaf(spln_b[k], wv, bp);
      }
      ws[OFF_SPC + j] = C; ws[OFF_SPB + j] = bp;
    }
  } else if (bid < 1629) {                // hm1 LN-fold
    const int j = (bid - 1627)*96 + tid;
    float C = 0.f, bp = hm1_b[j];
    for (int k = 0; k < 352; ++k) {
      const float wv = hm1_w[k*192 + j];
      const float wp = hln_g[k] * wv;
      ws[OFF_HM1P + k*192 + j] = wp;
      C += wp; bp = fmaf(hln_b[k], wv, bp);
    }
    ws[OFF_HMC + j] = C; ws[OFF_HMB + j] = bp;
  } else if (bid < 1631) {                // hq1 LN-fold
    const int j = (bid - 1629)*96 + tid;
    float C = 0.f, bp = hq1_b[j];
    for (int k = 0; k < 352; ++k) {
      const float wv = hq1_w[k*192 + j];
      const float wp = hln_g[k] * wv;
      ws[OFF_HQ1P + k*192 + j] = wp;
      C += wp; bp = fmaf(hln_b[k], wv, bp);
    }
    ws[OFF_HQC + j] = C; ws[OFF_HQB + j] = bp;
  } else {                                // hn1 LN-fold (96 cols)
    const int j = tid;
    float C = 0.f, bp = hn1_b[j];
    for (int k = 0; k < 352; ++k) {
      const float wv = hn1_w[k*96 + j];
      const float wp = hln_g[k] * wv;
      ws[OFF_HN1P + k*96 + j] = wp;
      C += wp; bp = fmaf(hln_b[k], wv, bp);
    }
    ws[OFF_HNC + j] = C; ws[OFF_HNB + j] = bp;
  }
}

// ---------------- K1: x-projection + 7-step recurrence ----------------
// 1 thread = 1 sample. z-row (raw [h|x], bf16) in private LDS row,
// stride 97 dwords => per-lane distinct banks. Weights via uniform
// (scalar) loads. Outputs [h_last|h_mean|h_max] as bf16 to ws feat.
__global__ __launch_bounds__(256) void k1_scan(
    const float* __restrict__ x_num, const int* __restrict__ x_cat,
    const float* __restrict__ h0,    const float* __restrict__ xproj_w,
    const float* __restrict__ fc2_w, const float* __restrict__ fc2_b,
    const float* __restrict__ ws,    unsigned short* __restrict__ feat)
{
  __shared__ unsigned short zbuf[256 * 194];   // 99328 B
  const int tid = threadIdx.x;
  const int s = blockIdx.x * 256 + tid;
  unsigned short* zrow = zbuf + tid * 194;
  const unsigned int* zw = (const unsigned int*)zbuf;
  const unsigned int zwb = (unsigned int)tid * 97u;

  float h[96], hsum[96], hmax[96];
  #pragma unroll
  for (int i = 0; i < 96; ++i) { h[i] = h0[i]; hsum[i] = 0.f; hmax[i] = -3.4e38f; }

  const float* tab2  = ws + OFF_TAB2;
  const float* fc1p  = ws + OFF_FC1P;
  const float* fc1C  = ws + OFF_FC1C;
  const float* fc1bp = ws + OFF_FC1B;

  for (int t = 0; t < 7; ++t) {
    int xc[16];
    #pragma unroll
    for (int c = 0; c < 16; ++c) xc[c] = x_cat[(s*7 + t)*16 + c];
    float xn[32];
    #pragma unroll
    for (int i = 0; i < 32; ++i) xn[i] = x_num[(s*7 + t)*32 + i];
    const float* bt = ws + OFF_BIAST + t*96;

    // ---- stage 0: x_t = bias_t + x_num @ Wx[0:32] + sum_c tab2[c][idx_c] ----
    float sx = 0.f, sxx = 0.f;
    for (int jj = 0; jj < 6; ++jj) {
      float acc[16];
      #pragma unroll
      for (int u = 0; u < 16; ++u) acc[u] = bt[jj*16 + u];
      #pragma unroll
      for (int k = 0; k < 32; ++k) {
        const float xk = xn[k];
        const float* wr = xproj_w + k*96 + jj*16;
        #pragma unroll
        for (int u = 0; u < 16; ++u) acc[u] = fmaf(xk, wr[u], acc[u]);
      }
      #pragma unroll
      for (int c = 0; c < 16; ++c) {
        const float* row = tab2 + (c*101 + xc[c])*96 + jj*16;
        #pragma unroll
        for (int u = 0; u < 16; ++u) acc[u] += row[u];
      }
      #pragma unroll
      for (int u = 0; u < 16; ++u) {
        const float v = acc[u];
        sx += v; sxx = fmaf(v, v, sxx);
        zrow[96 + jj*16 + u] = f2b(v);
      }
    }
    // ---- h part of z (raw) + LN stats ----
    float sh = 0.f, shh = 0.f;
    #pragma unroll
    for (int i = 0; i < 96; ++i) {
      const float v = h[i];
      sh += v; shh = fmaf(v, v, shh);
      zrow[i] = f2b(v);
    }
    const float m    = (sh + sx) * (1.f/192.f);
    const float var  = (shh + sxx) * (1.f/192.f) - m*m;
    const float rinv = rsqrtf(var + 1e-5f);

    // dh bias (DT=1): h += fc2_b, then accumulate gelu(hid_j)*fc2_w[j,:]
    #pragma unroll
    for (int i = 0; i < 96; ++i) h[i] += fc2_b[i];

    for (int jj = 0; jj < 12; ++jj) {
      float acc[16];
      #pragma unroll
      for (int u = 0; u < 16; ++u) acc[u] = 0.f;
      #pragma unroll 2
      for (int kk = 0; kk < 6; ++kk) {
        #pragma unroll
        for (int q = 0; q < 16; ++q) {
          const unsigned int wrd = zw[zwb + kk*16 + q];
          const float fl = __uint_as_float(wrd << 16);
          const float fh = __uint_as_float(wrd & 0xffff0000u);
          const int k0 = kk*32 + 2*q;
          const float* w0 = fc1p + k0*192 + jj*16;
          #pragma unroll
          for (int u = 0; u < 16; ++u) acc[u] = fmaf(fl, w0[u], acc[u]);
          #pragma unroll
          for (int u = 0; u < 16; ++u) acc[u] = fmaf(fh, w0[192 + u], acc[u]);
        }
      }
      #pragma unroll
      for (int u = 0; u < 16; ++u) {
        const int j = jj*16 + u;
        const float hid = fmaf(rinv, acc[u] - m*fc1C[j], fc1bp[j]);
        const float g = geluf(hid);
        const float* w2 = fc2_w + j*96;
        #pragma unroll
        for (int i = 0; i < 96; ++i) h[i] = fmaf(g, w2[i], h[i]);
      }
    }
    #pragma unroll
    for (int i = 0; i < 96; ++i) { hsum[i] += h[i]; hmax[i] = fmaxf(hmax[i], h[i]); }
  }

  unsigned int* fw = (unsigned int*)(feat + (size_t)s * 288);
  #pragma unroll
  for (int i = 0; i < 48; ++i)
    fw[i] = (unsigned int)f2b(h[2*i]) | ((unsigned int)f2b(h[2*i+1]) << 16);
  #pragma unroll
  for (int i = 0; i < 48; ++i)
    fw[48 + i] = (unsigned int)f2b(hsum[2*i]*(1.f/7.f)) | ((unsigned int)f2b(hsum[2*i+1]*(1.f/7.f)) << 16);
  #pragma unroll
  for (int i = 0; i < 48; ++i)
    fw[96 + i] = (unsigned int)f2b(hmax[2*i]) | ((unsigned int)f2b(hmax[2*i+1]) << 16);
}

// ---------------- K2: static MLP + z-LN + 3 heads ----------------
// 64 samples/block, 4 wave-workers per sample (w = tid>>6, wave-uniform).
__global__ __launch_bounds__(256) void k2_heads(
    const float* __restrict__ x_static,
    const float* __restrict__ sp2_w, const float* __restrict__ sp2_b,
    const float* __restrict__ base_w, const float* __restrict__ base_b,
    const float* __restrict__ hm2_w, const float* __restrict__ hm2_b,
    const float* __restrict__ hq2_w, const float* __restrict__ hq2_b,
    const float* __restrict__ hn2_w, const float* __restrict__ hn2_b,
    const float* __restrict__ ws, const unsigned short* __restrict__ feat,
    float* __restrict__ out)
{
  __shared__ unsigned short zbuf[64 * 354];    // 45312 B, stride 177 dwords
  __shared__ float statbuf[64][4];
  __shared__ float basebuf[64];
  __shared__ float headpart[64][3][4];
  const int tid = threadIdx.x;
  const int r = tid & 63;
  const int w = tid >> 6;
  const int s = blockIdx.x * 64 + r;
  unsigned short* zrow = zbuf + r * 354;
  unsigned int* zwr = (unsigned int*)zbuf + r * 177;

  if (w == 1) {
    // stage feat (h_last|h_mean|h_max) raw into z cols 0..287 + partial stats
    float sh = 0.f, shh = 0.f;
    const uint4* fp4 = (const uint4*)(feat + (size_t)s * 288);
    for (int q = 0; q < 36; ++q) {
      const uint4 v = fp4[q];
      unsigned int wd[4] = { v.x, v.y, v.z, v.w };
      #pragma unroll
      for (int e = 0; e < 4; ++e) {
        zwr[q*4 + e] = wd[e];
        const float a = __uint_as_float(wd[e] << 16);
        const float b = __uint_as_float(wd[e] & 0xffff0000u);
        sh += a + b; shh = fmaf(a, a, shh); shh = fmaf(b, b, shh);
      }
    }
    statbuf[r][0] = sh; statbuf[r][1] = shh;
  } else if (w == 0) {
    // static path: base + s64 = gelu(LN(xs)@sp1)@sp2 + sp2_b
    float xs[64];
    #pragma unroll
    for (int i = 0; i < 64; ++i) xs[i] = x_static[s*64 + i];
    float base = base_b[0];
    #pragma unroll
    for (int i = 0; i < 64; ++i) base = fmaf(xs[i], base_w[i], base);
    basebuf[r] = base;
    float sm = 0.f, sq = 0.f;
    #pragma unroll
    for (int i = 0; i < 64; ++i) { sm += xs[i]; sq = fmaf(xs[i], xs[i], sq); }
    const float ms = sm * (1.f/64.f);
    const float rs = rsqrtf(sq*(1.f/64.f) - ms*ms + 1e-5f);
    const float* sp1p = ws + OFF_SP1P;
    const float* spC  = ws + OFF_SPC;
    const float* spb  = ws + OFF_SPB;
    float s64[64];
    #pragma unroll
    for (int i = 0; i < 64; ++i) s64[i] = sp2_b[i];
    for (int jh = 0; jh < 8; ++jh) {
      float acc[16];
      #pragma unroll
      for (int u = 0; u < 16; ++u) acc[u] = 0.f;
      #pragma unroll
      for (int k = 0; k < 64; ++k) {
        const float xk = xs[k];
        const float* wr = sp1p + k*128 + jh*16;
        #pragma unroll
        for (int u = 0; u < 16; ++u) acc[u] = fmaf(xk, wr[u], acc[u]);
      }
      #pragma unroll
      for (int u = 0; u < 16; ++u) {
        const int j = jh*16 + u;
        const float hid = fmaf(rs, acc[u] - ms*spC[j], spb[j]);
        const float g = geluf(hid);
        const float* w2 = sp2_w + j*64;
        #pragma unroll
        for (int i = 0; i < 64; ++i) s64[i] = fmaf(g, w2[i], s64[i]);
      }
    }
    float sh = 0.f, shh = 0.f;
    #pragma unroll
    for (int i = 0; i < 64; ++i) {
      const float v = s64[i];
      sh += v; shh = fmaf(v, v, shh);
      zrow[288 + i] = f2b(v);
    }
    statbuf[r][2] = sh; statbuf[r][3] = shh;
  }
  __syncthreads();

  const float m    = (statbuf[r][0] + statbuf[r][2]) * (1.f/352.f);
  const float var  = (statbuf[r][1] + statbuf[r][3]) * (1.f/352.f) - m*m;
  const float rinv = rsqrtf(var + 1e-5f);

  // heads: 30 blocks of 16 output cols, strided across the 4 workers
  float p0 = 0.f, p1 = 0.f, p2 = 0.f;
  for (int blk = w; blk < 30; blk += 4) {
    int head, jj, ncols;
    const float *Wp, *Cv, *bp, *w2;
    if (blk < 12)      { head = 0; jj = blk;      ncols = 192; Wp = ws+OFF_HM1P; Cv = ws+OFF_HMC; bp = ws+OFF_HMB; w2 = hm2_w; }
    else if (blk < 24) { head = 1; jj = blk - 12; ncols = 192; Wp = ws+OFF_HQ1P; Cv = ws+OFF_HQC; bp = ws+OFF_HQB; w2 = hq2_w; }
    else               { head = 2; jj = blk - 24; ncols = 96;  Wp = ws+OFF_HN1P; Cv = ws+OFF_HNC; bp = ws+OFF_HNB; w2 = hn2_w; }
    float acc[16];
    #pragma unroll
    for (int u = 0; u < 16; ++u) acc[u] = 0.f;
    #pragma unroll 2
    for (int kk = 0; kk < 22; ++kk) {
      #pragma unroll
      for (int q = 0; q < 8; ++q) {
        const unsigned int wrd = zwr[kk*8 + q];
        const float fl = __uint_as_float(wrd << 16);
        const float fh = __uint_as_float(wrd & 0xffff0000u);
        const int k0 = kk*16 + 2*q;
        const float* r0 = Wp + k0*ncols + jj*16;
        #pragma unroll
        for (int u = 0; u < 16; ++u) acc[u] = fmaf(fl, r0[u], acc[u]);
        #pragma unroll
        for (int u = 0; u < 16; ++u) acc[u] = fmaf(fh, r0[ncols + u], acc[u]);
      }
    }
    float part = 0.f;
    #pragma unroll
    for (int u = 0; u < 16; ++u) {
      const int j = jj*16 + u;
      const float hid = fmaf(rinv, acc[u] - m*Cv[j], bp[j]);
      part = fmaf(geluf(hid), w2[j], part);
    }
    if (head == 0) p0 += part; else if (head == 1) p1 += part; else p2 += part;
  }
  headpart[r][0][w] = p0; headpart[r][1][w] = p1; headpart[r][2][w] = p2;
  __syncthreads();
  if (w == 0) {
    const float mean = basebuf[r] + hm2_b[0] + headpart[r][0][0] + headpart[r][0][1] + headpart[r][0][2] + headpart[r][0][3];
    const float q20  = basebuf[r] + hq2_b[0] + headpart[r][1][0] + headpart[r][1][1] + headpart[r][1][2] + headpart[r][1][3];
    const float neg  =              hn2_b[0] + headpart[r][2][0] + headpart[r][2][1] + headpart[r][2][2] + headpart[r][2][3];
    out[s] = mean; out[NB + s] = q20; out[2*NB + s] = neg;
  }
}

extern "C" void kernel_launch(void* const* d_in, const int* in_sizes, int n_in,
                              void* d_out, int out_size, void* d_ws, size_t ws_size,
                              hipStream_t stream) {
  (void)in_sizes; (void)n_in; (void)out_size; (void)ws_size;
  const float* x_num    = (const float*)d_in[0];
  const float* x_static = (const float*)d_in[1];
  const int*   x_cat    = (const int*)  d_in[2];
  const float* cat_emb  = (const float*)d_in[3];
  const float* day_emb  = (const float*)d_in[4];
  const float* xproj_w  = (const float*)d_in[5];
  const float* xproj_b  = (const float*)d_in[6];
  const float* h0       = (const float*)d_in[7];
  const float* bln_g    = (const float*)d_in[8];
  const float* bln_b    = (const float*)d_in[9];
  const float* fc1_w    = (const float*)d_in[10];
  const float* fc1_b    = (const float*)d_in[11];
  const float* fc2_w    = (const float*)d_in[12];
  const float* fc2_b    = (const float*)d_in[13];
  const float* spln_g   = (const float*)d_in[14];
  const float* spln_b   = (const float*)d_in[15];
  const float* sp1_w    = (const float*)d_in[16];
  const float* sp1_b    = (const float*)d_in[17];
  const float* sp2_w    = (const float*)d_in[18];
  const float* sp2_b    = (const float*)d_in[19];
  const float* base_w   = (const float*)d_in[20];
  const float* base_b   = (const float*)d_in[21];
  const float* hln_g    = (const float*)d_in[22];
  const float* hln_b    = (const float*)d_in[23];
  const float* hm1_w    = (const float*)d_in[24];
  const float* hm1_b    = (const float*)d_in[25];
  const float* hm2_w    = (const float*)d_in[26];
  const float* hm2_b    = (const float*)d_in[27];
  const float* hq1_w    = (const float*)d_in[28];
  const float* hq1_b    = (const float*)d_in[29];
  const float* hq2_w    = (const float*)d_in[30];
  const float* hq2_b    = (const float*)d_in[31];
  const float* hn1_w    = (const float*)d_in[32];
  const float* hn1_b    = (const float*)d_in[33];
  const float* hn2_w    = (const float*)d_in[34];
  const float* hn2_b    = (const float*)d_in[35];

  float* ws = (float*)d_ws;
  unsigned short* feat = (unsigned short*)(ws + OFF_FEAT);
  float* out = (float*)d_out;

  k0_pre<<<1632, 96, 0, stream>>>(cat_emb, day_emb, xproj_w, xproj_b,
      bln_g, bln_b, fc1_w, fc1_b, spln_g, spln_b, sp1_w, sp1_b,
      hln_g, hln_b, hm1_w, hm1_b, hq1_w, hq1_b, hn1_w, hn1_b, ws);
  k1_scan<<<256, 256, 0, stream>>>(x_num, x_cat, h0, xproj_w, fc2_w, fc2_b, ws, feat);
  k2_heads<<<1024, 256, 0, stream>>>(x_static, sp2_w, sp2_b, base_w, base_b,
      hm2_w, hm2_b, hq2_w, hq2_b, hn2_w, hn2_b, ws, feat, out);
}

// Round 2
// 2201.448 us; speedup vs baseline: 4.6762x; 4.6762x over previous
//
#include <hip/hip_runtime.h>
#include <math.h>

#define NB 65536

typedef __attribute__((ext_vector_type(8))) short bf16x8;
typedef __attribute__((ext_vector_type(4))) float f32x4;

// ---- ws byte offsets ----
#define O_TAB2   0         // u16 [16][101][96]           310272
#define O_BIAST  310272    // f32 [7][96]                 2688
#define O_FC1C   312960    // f32 [192]                   768
#define O_FC1BP  313728    // f32 [192]                   768
#define O_FC1FR  314496    // u16 [72][64][8]             73728
#define O_FC2FR  388224    // u16 [36][64][8]             36864
#define O_XPFR   425088    // u16 [6][64][8]              6144
#define O_HDFR   431232    // u16 [330][64][8]            337920
#define O_HDC    769152    // f32 [480]                   1920
#define O_HDBP   771072    // f32 [480]                   1920
#define O_W2C    772992    // f32 [480]                   1920
#define O_SP1P   774912    // f32 [64][128]               32768
#define O_SPC    807680    // f32 [128]                   512
#define O_SPB    808192    // f32 [128]                   512
#define O_FEAT   808960    // u16 [65536][288]            37748736

__device__ __forceinline__ unsigned short f2b(float x) {
  unsigned int u = __float_as_uint(x);
  u += 0x7fffu + ((u >> 16) & 1u);   // RNE bf16
  return (unsigned short)(u >> 16);
}
__device__ __forceinline__ float b2f(unsigned short u) {
  return __uint_as_float(((unsigned)u) << 16);
}
__device__ __forceinline__ float lo16(unsigned w){ return __uint_as_float(w << 16); }
__device__ __forceinline__ float hi16(unsigned w){ return __uint_as_float(w & 0xffff0000u); }
__device__ __forceinline__ float geluf(float x) {
  return 0.5f * x * (1.0f + erff(x * 0.70710678118654752f));
}

// =================== K0: fold + frag-pack all weights ===================
__global__ void k0_pre(
    const float* __restrict__ cat_emb, const float* __restrict__ day_emb,
    const float* __restrict__ xproj_w, const float* __restrict__ xproj_b,
    const float* __restrict__ bln_g, const float* __restrict__ bln_b,
    const float* __restrict__ fc1_w, const float* __restrict__ fc1_b,
    const float* __restrict__ fc2_w,
    const float* __restrict__ spln_g, const float* __restrict__ spln_b,
    const float* __restrict__ sp1_w, const float* __restrict__ sp1_b,
    const float* __restrict__ hln_g, const float* __restrict__ hln_b,
    const float* __restrict__ hm1_w, const float* __restrict__ hm1_b,
    const float* __restrict__ hq1_w, const float* __restrict__ hq1_b,
    const float* __restrict__ hn1_w, const float* __restrict__ hn1_b,
    const float* __restrict__ hm2_w, const float* __restrict__ hq2_w,
    const float* __restrict__ hn2_w,
    char* __restrict__ wsb)
{
  const int b = blockIdx.x, tid = threadIdx.x;
  if (b < 1616) {                     // pre-projected embedding table (bf16)
    if (tid < 96) {
      int c = b / 101, ix = b - c*101;
      float acc = 0.f;
      #pragma unroll
      for (int k = 0; k < 16; ++k)
        acc = fmaf(cat_emb[(c*101+ix)*16 + k], xproj_w[(32 + c*16 + k)*96 + tid], acc);
      ((unsigned short*)(wsb + O_TAB2))[(c*101+ix)*96 + tid] = f2b(acc);
    }
  } else if (b < 1623) {              // per-t bias (xproj_b + day part)
    if (tid < 96) {
      int t = b - 1616;
      float acc = xproj_b[tid];
      #pragma unroll
      for (int d = 0; d < 8; ++d)
        acc = fmaf(day_emb[(1+t)*8 + d], xproj_w[(288+d)*96 + tid], acc);
      ((float*)(wsb + O_BIAST))[t*96 + tid] = acc;
    }
  } else if (b < 1625) {              // fc1 LN-fold C / B'
    if (tid < 96) {
      int col = (b-1623)*96 + tid;
      float C = 0.f, Bp = fc1_b[col];
      for (int k = 0; k < 192; ++k) {
        float w = fc1_w[k*192 + col];
        C = fmaf(bln_g[k], w, C);
        Bp = fmaf(bln_b[k], w, Bp);
      }
      ((float*)(wsb + O_FC1C))[col] = C;
      ((float*)(wsb + O_FC1BP))[col] = Bp;
    }
  } else if (b < 1697) {              // fc1 frags [nt(12)][ks(6)]
    int seg = b - 1625, nt = seg / 6, ks = seg - nt*6;
    int ln = tid >> 3, j = tid & 7;
    int k = ks*32 + (ln>>4)*8 + j, col = nt*16 + (ln&15);
    ((unsigned short*)(wsb + O_FC1FR))[(seg*64 + ln)*8 + j] = f2b(bln_g[k]*fc1_w[k*192 + col]);
  } else if (b < 1733) {              // fc2 frags [nt(6)][ks(6)]
    int seg = b - 1697, nt = seg / 6, ks = seg - nt*6;
    int ln = tid >> 3, j = tid & 7;
    int k = ks*32 + (ln>>4)*8 + j, col = nt*16 + (ln&15);
    ((unsigned short*)(wsb + O_FC2FR))[(seg*64 + ln)*8 + j] = f2b(fc2_w[k*96 + col]);
  } else if (b < 1734) {              // xproj[0:32] frags [nt(6)]
    if (tid < 384) {
      int nt = tid >> 6, ln = tid & 63;
      int col = nt*16 + (ln&15);
      #pragma unroll
      for (int j = 0; j < 8; ++j) {
        int k = (ln>>4)*8 + j;
        ((unsigned short*)(wsb + O_XPFR))[(nt*64 + ln)*8 + j] = f2b(xproj_w[k*96 + col]);
      }
    }
  } else if (b < 2064) {              // head frags [nt(30)][ks(11)]
    int seg = b - 1734, nt = seg / 11, ks = seg - nt*11;
    int ln = tid >> 3, j = tid & 7;
    int k = ks*32 + (ln>>4)*8 + j, gcol = nt*16 + (ln&15);
    float w;
    if (gcol < 192) w = hm1_w[k*192 + gcol];
    else if (gcol < 384) w = hq1_w[k*192 + (gcol-192)];
    else w = hn1_w[k*96 + (gcol-384)];
    ((unsigned short*)(wsb + O_HDFR))[(seg*64 + ln)*8 + j] = f2b(hln_g[k]*w);
  } else if (b < 2065) {              // head C / B' / w2 concat
    if (tid < 480) {
      int gcol = tid;
      float C = 0.f, Bp, w2;
      if (gcol < 192) { Bp = hm1_b[gcol]; w2 = hm2_w[gcol]; }
      else if (gcol < 384) { Bp = hq1_b[gcol-192]; w2 = hq2_w[gcol-192]; }
      else { Bp = hn1_b[gcol-384]; w2 = hn2_w[gcol-384]; }
      for (int k = 0; k < 352; ++k) {
        float w;
        if (gcol < 192) w = hm1_w[k*192 + gcol];
        else if (gcol < 384) w = hq1_w[k*192 + (gcol-192)];
        else w = hn1_w[k*96 + (gcol-384)];
        C = fmaf(hln_g[k], w, C);
        Bp = fmaf(hln_b[k], w, Bp);
      }
      ((float*)(wsb + O_HDC))[gcol] = C;
      ((float*)(wsb + O_HDBP))[gcol] = Bp;
      ((float*)(wsb + O_W2C))[gcol] = w2;
    }
  } else {                            // sp1 LN-fold (fp32)
    if (tid < 128) {
      int col = tid;
      float C = 0.f, Bp = sp1_b[col];
      for (int k = 0; k < 64; ++k) {
        float w = sp1_w[k*128 + col];
        float wp = spln_g[k]*w;
        ((float*)(wsb + O_SP1P))[k*128 + col] = wp;
        C += wp;
        Bp = fmaf(spln_b[k], w, Bp);
      }
      ((float*)(wsb + O_SPC))[col] = C;
      ((float*)(wsb + O_SPB))[col] = Bp;
    }
  }
}

// =================== K1: fused x-proj + 7-step MFMA recurrence ===================
// 512 thr = 8 waves; each wave owns a 16-row M-tile end-to-end (no barriers in t-loop).
// zg LDS: [128 rows][stride 200 u16] holds z (h|x) then g. h/hsum/hmax in regs (C-layout).
__global__ __launch_bounds__(512, 2) void k1_scan(
    const float* __restrict__ x_num, const int* __restrict__ x_cat,
    const float* __restrict__ h0, const float* __restrict__ fc2_b,
    const char* __restrict__ wsb, unsigned short* __restrict__ feat)
{
  extern __shared__ char smem[];
  unsigned short* zg = (unsigned short*)smem;              // 51200 B
  unsigned short* f1f = (unsigned short*)(smem + 51200);   // 73728 B
  unsigned short* f2f = (unsigned short*)(smem + 124928);  // 36864 B
  float* statm = (float*)(smem + 161792);                  // [128][2]

  const int tid = threadIdx.x;
  const int wv = tid >> 6;
  const int l = tid & 63;
  const int lr = l & 15;
  const int lq = l >> 4;
  const int rowt = wv*16 + lr;
  const long s_q = (long)blockIdx.x*128 + rowt;

  { // stage frag tables to LDS
    const uint4* s1 = (const uint4*)(wsb + O_FC1FR);
    uint4* d1 = (uint4*)f1f;
    for (int o = tid; o < 4608; o += 512) d1[o] = s1[o];
    const uint4* s2 = (const uint4*)(wsb + O_FC2FR);
    uint4* d2 = (uint4*)f2f;
    for (int o = tid; o < 2304; o += 512) d2[o] = s2[o];
  }
  bf16x8 xpf[6];
  {
    const bf16x8* xp = (const bf16x8*)(wsb + O_XPFR);
    #pragma unroll
    for (int nt = 0; nt < 6; ++nt) xpf[nt] = xp[nt*64 + l];
  }
  const float* biast = (const float*)(wsb + O_BIAST);
  const unsigned short* tab2 = (const unsigned short*)(wsb + O_TAB2);
  const bf16x8* f1v = (const bf16x8*)f1f;
  const bf16x8* f2v = (const bf16x8*)f2f;

  float C1[12], B1[12];
  {
    const float* fc1C = (const float*)(wsb + O_FC1C);
    const float* fc1BP = (const float*)(wsb + O_FC1BP);
    #pragma unroll
    for (int nt = 0; nt < 12; ++nt) { C1[nt] = fc1C[nt*16+lr]; B1[nt] = fc1BP[nt*16+lr]; }
  }
  float fb2[6];
  #pragma unroll
  for (int nt = 0; nt < 6; ++nt) fb2[nt] = fc2_b[nt*16+lr];

  float h[24], hs[24], hm[24];
  #pragma unroll
  for (int nt = 0; nt < 6; ++nt) {
    float v = h0[nt*16+lr];
    #pragma unroll
    for (int i = 0; i < 4; ++i) { h[nt*4+i] = v; hs[nt*4+i] = 0.f; hm[nt*4+i] = -3.4e38f; }
  }
  __syncthreads();

  const f32x4 zero4 = {0.f, 0.f, 0.f, 0.f};

  for (int t = 0; t < 7; ++t) {
    const long base_ct = s_q*7 + t;
    // ---- (a) embedding gather (q-layout: row=lr-of-tile, cols lq*24..+23) ----
    int idx[16];
    {
      const int4* ip = (const int4*)(x_cat + base_ct*16);
      int4 i0 = ip[0], i1 = ip[1], i2 = ip[2], i3 = ip[3];
      idx[0]=i0.x; idx[1]=i0.y; idx[2]=i0.z; idx[3]=i0.w;
      idx[4]=i1.x; idx[5]=i1.y; idx[6]=i1.z; idx[7]=i1.w;
      idx[8]=i2.x; idx[9]=i2.y; idx[10]=i2.z; idx[11]=i2.w;
      idx[12]=i3.x; idx[13]=i3.y; idx[14]=i3.z; idx[15]=i3.w;
    }
    float ga[24];
    #pragma unroll
    for (int u = 0; u < 24; ++u) ga[u] = 0.f;
    #pragma unroll
    for (int c = 0; c < 16; ++c) {
      const uint4* tp = (const uint4*)tab2 + (c*101 + idx[c])*12 + lq*3;
      uint4 w0 = tp[0], w1 = tp[1], w2 = tp[2];
      unsigned wb[12] = {w0.x,w0.y,w0.z,w0.w, w1.x,w1.y,w1.z,w1.w, w2.x,w2.y,w2.z,w2.w};
      #pragma unroll
      for (int q = 0; q < 12; ++q) { ga[2*q] += lo16(wb[q]); ga[2*q+1] += hi16(wb[q]); }
    }
    {
      unsigned ow[12];
      #pragma unroll
      for (int q = 0; q < 12; ++q)
        ow[q] = (unsigned)f2b(ga[2*q]) | ((unsigned)f2b(ga[2*q+1]) << 16);
      uint4* zp = (uint4*)(zg + rowt*200 + 96 + lq*24);
      zp[0] = make_uint4(ow[0],ow[1],ow[2],ow[3]);
      zp[1] = make_uint4(ow[4],ow[5],ow[6],ow[7]);
      zp[2] = make_uint4(ow[8],ow[9],ow[10],ow[11]);
    }
    // ---- (b) x_num @ xproj[0:32] via MFMA, RMW into zg x-half + bias ----
    f32x4 xacc[6];
    {
      const float* xnp = x_num + base_ct*32 + lq*8;
      float xf[8];
      *(float4*)&xf[0] = *(const float4*)xnp;
      *(float4*)&xf[4] = *(const float4*)(xnp + 4);
      union { bf16x8 v; unsigned short u[8]; } au;
      #pragma unroll
      for (int j = 0; j < 8; ++j) au.u[j] = f2b(xf[j]);
      #pragma unroll
      for (int nt = 0; nt < 6; ++nt)
        xacc[nt] = __builtin_amdgcn_mfma_f32_16x16x32_bf16(au.v, xpf[nt], zero4, 0, 0, 0);
    }
    #pragma unroll
    for (int nt = 0; nt < 6; ++nt) {
      float bi = biast[t*96 + nt*16 + lr];
      #pragma unroll
      for (int i = 0; i < 4; ++i) {
        int zi = (wv*16 + lq*4 + i)*200 + 96 + nt*16 + lr;
        float v = b2f(zg[zi]) + xacc[nt][i] + bi;
        zg[zi] = f2b(v);
      }
    }
    // ---- (c) write h (bf16) into zg h-half ----
    #pragma unroll
    for (int nt = 0; nt < 6; ++nt) {
      #pragma unroll
      for (int i = 0; i < 4; ++i)
        zg[(wv*16 + lq*4 + i)*200 + nt*16 + lr] = f2b(h[nt*4+i]);
    }
    // ---- (d) LN stats over raw z (bf16) ----
    {
      float sm = 0.f, sq = 0.f;
      #pragma unroll
      for (int q6 = 0; q6 < 6; ++q6) {
        uint4 w = *(const uint4*)(zg + rowt*200 + lq*48 + q6*8);
        unsigned wb[4] = {w.x, w.y, w.z, w.w};
        #pragma unroll
        for (int e = 0; e < 4; ++e) {
          float a = lo16(wb[e]), bb = hi16(wb[e]);
          sm += a + bb; sq = fmaf(a, a, sq); sq = fmaf(bb, bb, sq);
        }
      }
      sm += __shfl_xor(sm, 16, 64); sm += __shfl_xor(sm, 32, 64);
      sq += __shfl_xor(sq, 16, 64); sq += __shfl_xor(sq, 32, 64);
      if (lq == 0) {
        float m = sm * (1.f/192.f);
        float var = sq * (1.f/192.f) - m*m;
        statm[rowt*2] = m;
        statm[rowt*2+1] = rsqrtf(var + 1e-5f);
      }
    }
    float mr[4], rr[4];
    #pragma unroll
    for (int i = 0; i < 4; ++i) {
      int r = wv*16 + lq*4 + i;
      mr[i] = statm[r*2]; rr[i] = statm[r*2+1];
    }
    // ---- (e) fc1 GEMM ----
    f32x4 acc[12];
    #pragma unroll
    for (int nt = 0; nt < 12; ++nt) acc[nt] = zero4;
    #pragma unroll
    for (int ks = 0; ks < 6; ++ks) {
      bf16x8 a = *(const bf16x8*)(zg + rowt*200 + ks*32 + lq*8);
      #pragma unroll
      for (int nt = 0; nt < 12; ++nt)
        acc[nt] = __builtin_amdgcn_mfma_f32_16x16x32_bf16(a, f1v[(nt*6+ks)*64 + l], acc[nt], 0, 0, 0);
    }
    // ---- (f) LN-finish + gelu -> g into zg ----
    #pragma unroll
    for (int nt = 0; nt < 12; ++nt) {
      #pragma unroll
      for (int i = 0; i < 4; ++i) {
        float hid = rr[i]*(acc[nt][i] - mr[i]*C1[nt]) + B1[nt];
        zg[(wv*16 + lq*4 + i)*200 + nt*16 + lr] = f2b(geluf(hid));
      }
    }
    // ---- (g) fc2 GEMM ----
    f32x4 a2[6];
    #pragma unroll
    for (int nt = 0; nt < 6; ++nt) a2[nt] = zero4;
    #pragma unroll
    for (int ks = 0; ks < 6; ++ks) {
      bf16x8 a = *(const bf16x8*)(zg + rowt*200 + ks*32 + lq*8);
      #pragma unroll
      for (int nt = 0; nt < 6; ++nt)
        a2[nt] = __builtin_amdgcn_mfma_f32_16x16x32_bf16(a, f2v[(nt*6+ks)*64 + l], a2[nt], 0, 0, 0);
    }
    // ---- (h) h update + running mean/max ----
    #pragma unroll
    for (int nt = 0; nt < 6; ++nt) {
      #pragma unroll
      for (int i = 0; i < 4; ++i) {
        int u = nt*4 + i;
        h[u] += a2[nt][i] + fb2[nt];
        hs[u] += h[u];
        hm[u] = fmaxf(hm[u], h[u]);
      }
    }
  }
  // ---- feat out: [h_last | h_mean | h_max] bf16 ----
  #pragma unroll
  for (int nt = 0; nt < 6; ++nt) {
    #pragma unroll
    for (int i = 0; i < 4; ++i) {
      size_t r = ((size_t)blockIdx.x*128 + wv*16 + lq*4 + i)*288;
      int c = nt*16 + lr;
      feat[r + c] = f2b(h[nt*4+i]);
      feat[r + 96 + c] = f2b(hs[nt*4+i]*(1.f/7.f));
      feat[r + 192 + c] = f2b(hm[nt*4+i]);
    }
  }
}

// =================== K2: static MLP + z-LN + 3 heads (MFMA) ===================
__global__ __launch_bounds__(512, 2) void k2_heads(
    const float* __restrict__ x_static, const float* __restrict__ sp2_w,
    const float* __restrict__ sp2_b, const float* __restrict__ base_w,
    const float* __restrict__ base_b, const float* __restrict__ hm2_b,
    const float* __restrict__ hq2_b, const float* __restrict__ hn2_b,
    const char* __restrict__ wsb, const unsigned short* __restrict__ feat,
    float* __restrict__ out)
{
  extern __shared__ char smem[];
  unsigned short* z = (unsigned short*)smem;               // [128][360] u16
  unsigned short* gh = (unsigned short*)(smem + 92160);    // [128][136] u16
  float* part = (float*)(smem + 126976);                   // [128][3][8]
  float* statm = (float*)(smem + 139264);                  // [128][2]
  float* baseb = (float*)(smem + 140288);                  // [128]

  const int tid = threadIdx.x;
  const int wv = tid >> 6;
  const int l = tid & 63;
  const int lr = l & 15;
  const int lq = l >> 4;
  const int s0 = blockIdx.x*128;

  for (int o = tid; o < 3072; o += 512) part[o] = 0.f;

  { // feat -> z cols 0..287
    const uint4* fs = (const uint4*)(feat + (size_t)s0*288);
    for (int o = tid; o < 4608; o += 512) {
      int r = o / 36, u = o - r*36;
      *(uint4*)(z + r*360 + u*8) = fs[o];
    }
  }
  // ---- static MLP stage 1 (4 threads/row) ----
  const int r4 = tid >> 2, p4 = tid & 3;
  {
    const float4* xp = (const float4*)(x_static + (size_t)(s0 + r4)*64);
    float xv[64];
    #pragma unroll
    for (int q = 0; q < 16; ++q) *(float4*)&xv[q*4] = xp[q];
    float sm = 0.f, sq = 0.f;
    #pragma unroll
    for (int k = 0; k < 64; ++k) { sm += xv[k]; sq = fmaf(xv[k], xv[k], sq); }
    float ms = sm*(1.f/64.f);
    float rs = rsqrtf(sq*(1.f/64.f) - ms*ms + 1e-5f);
    if (p4 == 0) {
      float bs = base_b[0];
      #pragma unroll
      for (int k = 0; k < 64; ++k) bs = fmaf(xv[k], base_w[k], bs);
      baseb[r4] = bs;
    }
    const float* sp1p = (const float*)(wsb + O_SP1P);
    const float* spC = (const float*)(wsb + O_SPC);
    const float* spB = (const float*)(wsb + O_SPB);
    float a1[32];
    #pragma unroll
    for (int u = 0; u < 32; ++u) a1[u] = 0.f;
    for (int k = 0; k < 64; ++k) {
      const float4* wr = (const float4*)(sp1p + k*128 + p4*32);
      float xk = xv[k];
      #pragma unroll
      for (int q = 0; q < 8; ++q) {
        float4 w = wr[q];
        a1[q*4+0] = fmaf(xk, w.x, a1[q*4+0]);
        a1[q*4+1] = fmaf(xk, w.y, a1[q*4+1]);
        a1[q*4+2] = fmaf(xk, w.z, a1[q*4+2]);
        a1[q*4+3] = fmaf(xk, w.w, a1[q*4+3]);
      }
    }
    #pragma unroll
    for (int u = 0; u < 16; ++u) {
      int j0 = p4*32 + 2*u;
      float g0 = geluf(rs*(a1[2*u]   - ms*spC[j0])   + spB[j0]);
      float g1 = geluf(rs*(a1[2*u+1] - ms*spC[j0+1]) + spB[j0+1]);
      *(unsigned*)(gh + r4*136 + j0) = (unsigned)f2b(g0) | ((unsigned)f2b(g1) << 16);
    }
  }
  __syncthreads();
  // ---- static MLP stage 2 -> s64 into z cols 288..351 ----
  {
    float a2[16];
    #pragma unroll
    for (int u = 0; u < 16; ++u) a2[u] = sp2_b[p4*16+u];
    #pragma unroll 4
    for (int kk = 0; kk < 16; ++kk) {
      uint4 gw = *(const uint4*)(gh + r4*136 + kk*8);
      unsigned wb[4] = {gw.x, gw.y, gw.z, gw.w};
      #pragma unroll
      for (int e = 0; e < 4; ++e) {
        float gl = lo16(wb[e]), ghv = hi16(wb[e]);
        int k0 = kk*8 + 2*e;
        const float4* w0 = (const float4*)(sp2_w + k0*64 + p4*16);
        const float4* w1 = (const float4*)(sp2_w + (k0+1)*64 + p4*16);
        #pragma unroll
        for (int q = 0; q < 4; ++q) {
          float4 wa = w0[q], wbq = w1[q];
          a2[q*4+0] = fmaf(gl, wa.x, fmaf(ghv, wbq.x, a2[q*4+0]));
          a2[q*4+1] = fmaf(gl, wa.y, fmaf(ghv, wbq.y, a2[q*4+1]));
          a2[q*4+2] = fmaf(gl, wa.z, fmaf(ghv, wbq.z, a2[q*4+2]));
          a2[q*4+3] = fmaf(gl, wa.w, fmaf(ghv, wbq.w, a2[q*4+3]));
        }
      }
    }
    #pragma unroll
    for (int u = 0; u < 8; ++u) {
      int j0 = p4*16 + 2*u;
      *(unsigned*)(z + r4*360 + 288 + j0) =
          (unsigned)f2b(a2[2*u]) | ((unsigned)f2b(a2[2*u+1]) << 16);
    }
  }
  __syncthreads();
  // ---- z stats ----
  {
    float sm = 0.f, sq = 0.f;
    #pragma unroll
    for (int q = 0; q < 11; ++q) {
      uint4 w = *(const uint4*)(z + r4*360 + p4*88 + q*8);
      unsigned wb[4] = {w.x, w.y, w.z, w.w};
      #pragma unroll
      for (int e = 0; e < 4; ++e) {
        float a = lo16(wb[e]), bb = hi16(wb[e]);
        sm += a + bb; sq = fmaf(a, a, sq); sq = fmaf(bb, bb, sq);
      }
    }
    sm += __shfl_xor(sm, 1, 64); sm += __shfl_xor(sm, 2, 64);
    sq += __shfl_xor(sq, 1, 64); sq += __shfl_xor(sq, 2, 64);
    if (p4 == 0) {
      float m = sm*(1.f/352.f);
      float var = sq*(1.f/352.f) - m*m;
      statm[r4*2] = m; statm[r4*2+1] = rsqrtf(var + 1e-5f);
    }
  }
  __syncthreads();
  // ---- phase B: head GEMMs (B-frags streamed from L2) ----
  {
    const float* hdC = (const float*)(wsb + O_HDC);
    const float* hdB = (const float*)(wsb + O_HDBP);
    const float* w2c = (const float*)(wsb + O_W2C);
    const bf16x8* hv = (const bf16x8*)(wsb + O_HDFR);
    int ntbeg = wv < 6 ? wv*4 : (wv == 6 ? 24 : 27);
    int ntn = wv < 6 ? 4 : 3;
    int head = wv < 3 ? 0 : (wv < 6 ? 1 : 2);
    float mrw[32], rrw[32];
    #pragma unroll
    for (int mt = 0; mt < 8; ++mt) {
      #pragma unroll
      for (int i = 0; i < 4; ++i) {
        int r = mt*16 + lq*4 + i;
        mrw[mt*4+i] = statm[r*2]; rrw[mt*4+i] = statm[r*2+1];
      }
    }
    const f32x4 zero4 = {0.f, 0.f, 0.f, 0.f};
    float pr[32];
    #pragma unroll
    for (int u = 0; u < 32; ++u) pr[u] = 0.f;
    for (int ntk = 0; ntk < ntn; ++ntk) {
      int nt = ntbeg + ntk;
      float Cg = hdC[nt*16+lr], Bg = hdB[nt*16+lr], w2 = w2c[nt*16+lr];
      f32x4 acc[8];
      #pragma unroll
      for (int mt = 0; mt < 8; ++mt) acc[mt] = zero4;
      for (int ks = 0; ks < 11; ++ks) {
        bf16x8 bfr = hv[(nt*11+ks)*64 + l];
        #pragma unroll
        for (int mt = 0; mt < 8; ++mt) {
          bf16x8 a = *(const bf16x8*)(z + (mt*16+lr)*360 + ks*32 + lq*8);
          acc[mt] = __builtin_amdgcn_mfma_f32_16x16x32_bf16(a, bfr, acc[mt], 0, 0, 0);
        }
      }
      #pragma unroll
      for (int mt = 0; mt < 8; ++mt) {
        #pragma unroll
        for (int i = 0; i < 4; ++i) {
          int u = mt*4 + i;
          float hid = rrw[u]*(acc[mt][i] - mrw[u]*Cg) + Bg;
          pr[u] += geluf(hid)*w2;
        }
      }
    }
    #pragma unroll
    for (int u = 0; u < 32; ++u) {
      pr[u] += __shfl_xor(pr[u], 1, 64);
      pr[u] += __shfl_xor(pr[u], 2, 64);
      pr[u] += __shfl_xor(pr[u], 4, 64);
      pr[u] += __shfl_xor(pr[u], 8, 64);
    }
    if (lr == 0) {
      #pragma unroll
      for (int mt = 0; mt < 8; ++mt) {
        #pragma unroll
        for (int i = 0; i < 4; ++i)
          part[(mt*16 + lq*4 + i)*24 + head*8 + wv] = pr[mt*4+i];
      }
    }
  }
  __syncthreads();
  if (tid < 128) {
    float p0 = 0.f, p1 = 0.f, p2 = 0.f;
    #pragma unroll
    for (int w = 0; w < 8; ++w) {
      p0 += part[tid*24 + w];
      p1 += part[tid*24 + 8 + w];
      p2 += part[tid*24 + 16 + w];
    }
    float bs = baseb[tid];
    int s = s0 + tid;
    out[s] = bs + hm2_b[0] + p0;
    out[NB + s] = bs + hq2_b[0] + p1;
    out[2*NB + s] = hn2_b[0] + p2;
  }
}

extern "C" void kernel_launch(void* const* d_in, const int* in_sizes, int n_in,
                              void* d_out, int out_size, void* d_ws, size_t ws_size,
                              hipStream_t stream) {
  (void)in_sizes; (void)n_in; (void)out_size; (void)ws_size;
  const float* x_num    = (const float*)d_in[0];
  const float* x_static = (const float*)d_in[1];
  const int*   x_cat    = (const int*)  d_in[2];
  const float* cat_emb  = (const float*)d_in[3];
  const float* day_emb  = (const float*)d_in[4];
  const float* xproj_w  = (const float*)d_in[5];
  const float* xproj_b  = (const float*)d_in[6];
  const float* h0       = (const float*)d_in[7];
  const float* bln_g    = (const float*)d_in[8];
  const float* bln_b    = (const float*)d_in[9];
  const float* fc1_w    = (const float*)d_in[10];
  const float* fc1_b    = (const float*)d_in[11];
  const float* fc2_w    = (const float*)d_in[12];
  const float* fc2_b    = (const float*)d_in[13];
  const float* spln_g   = (const float*)d_in[14];
  const float* spln_b   = (const float*)d_in[15];
  const float* sp1_w    = (const float*)d_in[16];
  const float* sp1_b    = (const float*)d_in[17];
  const float* sp2_w    = (const float*)d_in[18];
  const float* sp2_b    = (const float*)d_in[19];
  const float* base_w   = (const float*)d_in[20];
  const float* base_b   = (const float*)d_in[21];
  const float* hln_g    = (const float*)d_in[22];
  const float* hln_b    = (const float*)d_in[23];
  const float* hm1_w    = (const float*)d_in[24];
  const float* hm1_b    = (const float*)d_in[25];
  const float* hm2_w    = (const float*)d_in[26];
  const float* hm2_b    = (const float*)d_in[27];
  const float* hq1_w    = (const float*)d_in[28];
  const float* hq1_b    = (const float*)d_in[29];
  const float* hq2_w    = (const float*)d_in[30];
  const float* hq2_b    = (const float*)d_in[31];
  const float* hn1_w    = (const float*)d_in[32];
  const float* hn1_b    = (const float*)d_in[33];
  const float* hn2_w    = (const float*)d_in[34];
  const float* hn2_b    = (const float*)d_in[35];

  char* wsb = (char*)d_ws;
  unsigned short* feat = (unsigned short*)(wsb + O_FEAT);
  float* out = (float*)d_out;

  k0_pre<<<2066, 512, 0, stream>>>(cat_emb, day_emb, xproj_w, xproj_b,
      bln_g, bln_b, fc1_w, fc1_b, fc2_w, spln_g, spln_b, sp1_w, sp1_b,
      hln_g, hln_b, hm1_w, hm1_b, hq1_w, hq1_b, hn1_w, hn1_b,
      hm2_w, hq2_w, hn2_w, wsb);
  k1_scan<<<512, 512, 162816, stream>>>(x_num, x_cat, h0, fc2_b, wsb, feat);
  k2_heads<<<512, 512, 140800, stream>>>(x_static, sp2_w, sp2_b, base_w, base_b,
      hm2_b, hq2_b, hn2_b, wsb, feat, out);
}

// Round 3
// 1963.883 us; speedup vs baseline: 5.2419x; 1.1210x over previous
//
#include <hip/hip_runtime.h>
#include <math.h>

#define NB 65536

typedef __attribute__((ext_vector_type(8))) short bf16x8;
typedef __attribute__((ext_vector_type(4))) float f32x4;

// ---- ws byte offsets ----
#define O_TAB2   0         // u16 [16][101][96]           310272
#define O_BIAST  310272    // f32 [7][96]                 2688
#define O_FC1C   312960    // f32 [192]                   768
#define O_FC1BP  313728    // f32 [192]                   768
#define O_FC1FR  314496    // u16 [72][64][8]             73728
#define O_FC2FR  388224    // u16 [36][64][8]             36864
#define O_XPFR   425088    // u16 [6][64][8]              6144
#define O_HDFR   431232    // u16 [330][64][8]            337920
#define O_HDC    769152    // f32 [480]                   1920
#define O_HDBP   771072    // f32 [480]                   1920
#define O_W2C    772992    // f32 [480]                   1920
#define O_SP1P   774912    // f32 [64][128]               32768
#define O_SPC    807680    // f32 [128]                   512
#define O_SPB    808192    // f32 [128]                   512
#define O_FEAT   808960    // u16 [65536][288]            37748736
#define O_S64    38557696  // u16 [65536][64]             8388608
#define O_STAT   46946304  // f32 [65536][2]              524288
#define O_BASE   47470592  // f32 [65536]                 262144

__device__ __forceinline__ unsigned short f2b(float x) {
  unsigned int u = __float_as_uint(x);
  u += 0x7fffu + ((u >> 16) & 1u);   // RNE bf16
  return (unsigned short)(u >> 16);
}
__device__ __forceinline__ float b2f(unsigned short u) {
  return __uint_as_float(((unsigned)u) << 16);
}
__device__ __forceinline__ float lo16(unsigned w){ return __uint_as_float(w << 16); }
__device__ __forceinline__ float hi16(unsigned w){ return __uint_as_float(w & 0xffff0000u); }
__device__ __forceinline__ float geluf(float x) {
  return 0.5f * x * (1.0f + erff(x * 0.70710678118654752f));
}

// =================== K0: fold + frag-pack all weights ===================
__global__ void k0_pre(
    const float* __restrict__ cat_emb, const float* __restrict__ day_emb,
    const float* __restrict__ xproj_w, const float* __restrict__ xproj_b,
    const float* __restrict__ bln_g, const float* __restrict__ bln_b,
    const float* __restrict__ fc1_w, const float* __restrict__ fc1_b,
    const float* __restrict__ fc2_w,
    const float* __restrict__ spln_g, const float* __restrict__ spln_b,
    const float* __restrict__ sp1_w, const float* __restrict__ sp1_b,
    const float* __restrict__ hln_g, const float* __restrict__ hln_b,
    const float* __restrict__ hm1_w, const float* __restrict__ hm1_b,
    const float* __restrict__ hq1_w, const float* __restrict__ hq1_b,
    const float* __restrict__ hn1_w, const float* __restrict__ hn1_b,
    const float* __restrict__ hm2_w, const float* __restrict__ hq2_w,
    const float* __restrict__ hn2_w,
    char* __restrict__ wsb)
{
  const int b = blockIdx.x, tid = threadIdx.x;
  if (b < 1616) {                     // pre-projected embedding table (bf16)
    if (tid < 96) {
      int c = b / 101, ix = b - c*101;
      float acc = 0.f;
      #pragma unroll
      for (int k = 0; k < 16; ++k)
        acc = fmaf(cat_emb[(c*101+ix)*16 + k], xproj_w[(32 + c*16 + k)*96 + tid], acc);
      ((unsigned short*)(wsb + O_TAB2))[(c*101+ix)*96 + tid] = f2b(acc);
    }
  } else if (b < 1623) {              // per-t bias (xproj_b + day part)
    if (tid < 96) {
      int t = b - 1616;
      float acc = xproj_b[tid];
      #pragma unroll
      for (int d = 0; d < 8; ++d)
        acc = fmaf(day_emb[(1+t)*8 + d], xproj_w[(288+d)*96 + tid], acc);
      ((float*)(wsb + O_BIAST))[t*96 + tid] = acc;
    }
  } else if (b < 1625) {              // fc1 LN-fold C / B'
    if (tid < 96) {
      int col = (b-1623)*96 + tid;
      float C = 0.f, Bp = fc1_b[col];
      for (int k = 0; k < 192; ++k) {
        float w = fc1_w[k*192 + col];
        C = fmaf(bln_g[k], w, C);
        Bp = fmaf(bln_b[k], w, Bp);
      }
      ((float*)(wsb + O_FC1C))[col] = C;
      ((float*)(wsb + O_FC1BP))[col] = Bp;
    }
  } else if (b < 1697) {              // fc1 frags [nt(12)][ks(6)]
    int seg = b - 1625, nt = seg / 6, ks = seg - nt*6;
    int ln = tid >> 3, j = tid & 7;
    int k = ks*32 + (ln>>4)*8 + j, col = nt*16 + (ln&15);
    ((unsigned short*)(wsb + O_FC1FR))[(seg*64 + ln)*8 + j] = f2b(bln_g[k]*fc1_w[k*192 + col]);
  } else if (b < 1733) {              // fc2 frags [nt(6)][ks(6)]
    int seg = b - 1697, nt = seg / 6, ks = seg - nt*6;
    int ln = tid >> 3, j = tid & 7;
    int k = ks*32 + (ln>>4)*8 + j, col = nt*16 + (ln&15);
    ((unsigned short*)(wsb + O_FC2FR))[(seg*64 + ln)*8 + j] = f2b(fc2_w[k*96 + col]);
  } else if (b < 1734) {              // xproj[0:32] frags [nt(6)]
    if (tid < 384) {
      int nt = tid >> 6, ln = tid & 63;
      int col = nt*16 + (ln&15);
      #pragma unroll
      for (int j = 0; j < 8; ++j) {
        int k = (ln>>4)*8 + j;
        ((unsigned short*)(wsb + O_XPFR))[(nt*64 + ln)*8 + j] = f2b(xproj_w[k*96 + col]);
      }
    }
  } else if (b < 2064) {              // head frags [nt(30)][ks(11)]
    int seg = b - 1734, nt = seg / 11, ks = seg - nt*11;
    int ln = tid >> 3, j = tid & 7;
    int k = ks*32 + (ln>>4)*8 + j, gcol = nt*16 + (ln&15);
    float w;
    if (gcol < 192) w = hm1_w[k*192 + gcol];
    else if (gcol < 384) w = hq1_w[k*192 + (gcol-192)];
    else w = hn1_w[k*96 + (gcol-384)];
    ((unsigned short*)(wsb + O_HDFR))[(seg*64 + ln)*8 + j] = f2b(hln_g[k]*w);
  } else if (b < 2065) {              // head C / B' / w2 concat
    if (tid < 480) {
      int gcol = tid;
      float C = 0.f, Bp, w2;
      if (gcol < 192) { Bp = hm1_b[gcol]; w2 = hm2_w[gcol]; }
      else if (gcol < 384) { Bp = hq1_b[gcol-192]; w2 = hq2_w[gcol-192]; }
      else { Bp = hn1_b[gcol-384]; w2 = hn2_w[gcol-384]; }
      for (int k = 0; k < 352; ++k) {
        float w;
        if (gcol < 192) w = hm1_w[k*192 + gcol];
        else if (gcol < 384) w = hq1_w[k*192 + (gcol-192)];
        else w = hn1_w[k*96 + (gcol-384)];
        C = fmaf(hln_g[k], w, C);
        Bp = fmaf(hln_b[k], w, Bp);
      }
      ((float*)(wsb + O_HDC))[gcol] = C;
      ((float*)(wsb + O_HDBP))[gcol] = Bp;
      ((float*)(wsb + O_W2C))[gcol] = w2;
    }
  } else {                            // sp1 LN-fold (fp32)
    if (tid < 128) {
      int col = tid;
      float C = 0.f, Bp = sp1_b[col];
      for (int k = 0; k < 64; ++k) {
        float w = sp1_w[k*128 + col];
        float wp = spln_g[k]*w;
        ((float*)(wsb + O_SP1P))[k*128 + col] = wp;
        C += wp;
        Bp = fmaf(spln_b[k], w, Bp);
      }
      ((float*)(wsb + O_SPC))[col] = C;
      ((float*)(wsb + O_SPB))[col] = Bp;
    }
  }
}

// =================== K1: fused x-proj + 7-step MFMA recurrence ===================
__global__ __launch_bounds__(512, 2) void k1_scan(
    const float* __restrict__ x_num, const int* __restrict__ x_cat,
    const float* __restrict__ h0, const float* __restrict__ fc2_b,
    const char* __restrict__ wsb, unsigned short* __restrict__ feat)
{
  extern __shared__ char smem[];
  unsigned short* zg = (unsigned short*)smem;              // 51200 B
  unsigned short* f1f = (unsigned short*)(smem + 51200);   // 73728 B
  unsigned short* f2f = (unsigned short*)(smem + 124928);  // 36864 B
  float* statm = (float*)(smem + 161792);                  // [128][2]

  const int tid = threadIdx.x;
  const int wv = tid >> 6;
  const int l = tid & 63;
  const int lr = l & 15;
  const int lq = l >> 4;
  const int rowt = wv*16 + lr;
  const long s_q = (long)blockIdx.x*128 + rowt;

  { // stage frag tables to LDS
    const uint4* s1 = (const uint4*)(wsb + O_FC1FR);
    uint4* d1 = (uint4*)f1f;
    for (int o = tid; o < 4608; o += 512) d1[o] = s1[o];
    const uint4* s2 = (const uint4*)(wsb + O_FC2FR);
    uint4* d2 = (uint4*)f2f;
    for (int o = tid; o < 2304; o += 512) d2[o] = s2[o];
  }
  bf16x8 xpf[6];
  {
    const bf16x8* xp = (const bf16x8*)(wsb + O_XPFR);
    #pragma unroll
    for (int nt = 0; nt < 6; ++nt) xpf[nt] = xp[nt*64 + l];
  }
  const float* biast = (const float*)(wsb + O_BIAST);
  const unsigned short* tab2 = (const unsigned short*)(wsb + O_TAB2);
  const bf16x8* f1v = (const bf16x8*)f1f;
  const bf16x8* f2v = (const bf16x8*)f2f;

  float C1[12], B1[12];
  {
    const float* fc1C = (const float*)(wsb + O_FC1C);
    const float* fc1BP = (const float*)(wsb + O_FC1BP);
    #pragma unroll
    for (int nt = 0; nt < 12; ++nt) { C1[nt] = fc1C[nt*16+lr]; B1[nt] = fc1BP[nt*16+lr]; }
  }
  float fb2[6];
  #pragma unroll
  for (int nt = 0; nt < 6; ++nt) fb2[nt] = fc2_b[nt*16+lr];

  float h[24], hs[24], hm[24];
  #pragma unroll
  for (int nt = 0; nt < 6; ++nt) {
    float v = h0[nt*16+lr];
    #pragma unroll
    for (int i = 0; i < 4; ++i) { h[nt*4+i] = v; hs[nt*4+i] = 0.f; hm[nt*4+i] = -3.4e38f; }
  }
  __syncthreads();

  const f32x4 zero4 = {0.f, 0.f, 0.f, 0.f};

  for (int t = 0; t < 7; ++t) {
    const long base_ct = s_q*7 + t;
    // ---- (a) embedding gather ----
    int idx[16];
    {
      const int4* ip = (const int4*)(x_cat + base_ct*16);
      int4 i0 = ip[0], i1 = ip[1], i2 = ip[2], i3 = ip[3];
      idx[0]=i0.x; idx[1]=i0.y; idx[2]=i0.z; idx[3]=i0.w;
      idx[4]=i1.x; idx[5]=i1.y; idx[6]=i1.z; idx[7]=i1.w;
      idx[8]=i2.x; idx[9]=i2.y; idx[10]=i2.z; idx[11]=i2.w;
      idx[12]=i3.x; idx[13]=i3.y; idx[14]=i3.z; idx[15]=i3.w;
    }
    float ga[24];
    #pragma unroll
    for (int u = 0; u < 24; ++u) ga[u] = 0.f;
    #pragma unroll
    for (int c = 0; c < 16; ++c) {
      const uint4* tp = (const uint4*)tab2 + (c*101 + idx[c])*12 + lq*3;
      uint4 w0 = tp[0], w1 = tp[1], w2 = tp[2];
      unsigned wb[12] = {w0.x,w0.y,w0.z,w0.w, w1.x,w1.y,w1.z,w1.w, w2.x,w2.y,w2.z,w2.w};
      #pragma unroll
      for (int q = 0; q < 12; ++q) { ga[2*q] += lo16(wb[q]); ga[2*q+1] += hi16(wb[q]); }
    }
    {
      unsigned ow[12];
      #pragma unroll
      for (int q = 0; q < 12; ++q)
        ow[q] = (unsigned)f2b(ga[2*q]) | ((unsigned)f2b(ga[2*q+1]) << 16);
      uint4* zp = (uint4*)(zg + rowt*200 + 96 + lq*24);
      zp[0] = make_uint4(ow[0],ow[1],ow[2],ow[3]);
      zp[1] = make_uint4(ow[4],ow[5],ow[6],ow[7]);
      zp[2] = make_uint4(ow[8],ow[9],ow[10],ow[11]);
    }
    // ---- (b) x_num @ xproj[0:32] via MFMA ----
    f32x4 xacc[6];
    {
      const float* xnp = x_num + base_ct*32 + lq*8;
      float xf[8];
      *(float4*)&xf[0] = *(const float4*)xnp;
      *(float4*)&xf[4] = *(const float4*)(xnp + 4);
      union { bf16x8 v; unsigned short u[8]; } au;
      #pragma unroll
      for (int j = 0; j < 8; ++j) au.u[j] = f2b(xf[j]);
      #pragma unroll
      for (int nt = 0; nt < 6; ++nt)
        xacc[nt] = __builtin_amdgcn_mfma_f32_16x16x32_bf16(au.v, xpf[nt], zero4, 0, 0, 0);
    }
    #pragma unroll
    for (int nt = 0; nt < 6; ++nt) {
      float bi = biast[t*96 + nt*16 + lr];
      #pragma unroll
      for (int i = 0; i < 4; ++i) {
        int zi = (wv*16 + lq*4 + i)*200 + 96 + nt*16 + lr;
        float v = b2f(zg[zi]) + xacc[nt][i] + bi;
        zg[zi] = f2b(v);
      }
    }
    // ---- (c) write h into zg h-half ----
    #pragma unroll
    for (int nt = 0; nt < 6; ++nt) {
      #pragma unroll
      for (int i = 0; i < 4; ++i)
        zg[(wv*16 + lq*4 + i)*200 + nt*16 + lr] = f2b(h[nt*4+i]);
    }
    // ---- (d) LN stats ----
    {
      float sm = 0.f, sq = 0.f;
      #pragma unroll
      for (int q6 = 0; q6 < 6; ++q6) {
        uint4 w = *(const uint4*)(zg + rowt*200 + lq*48 + q6*8);
        unsigned wb[4] = {w.x, w.y, w.z, w.w};
        #pragma unroll
        for (int e = 0; e < 4; ++e) {
          float a = lo16(wb[e]), bb = hi16(wb[e]);
          sm += a + bb; sq = fmaf(a, a, sq); sq = fmaf(bb, bb, sq);
        }
      }
      sm += __shfl_xor(sm, 16, 64); sm += __shfl_xor(sm, 32, 64);
      sq += __shfl_xor(sq, 16, 64); sq += __shfl_xor(sq, 32, 64);
      if (lq == 0) {
        float m = sm * (1.f/192.f);
        float var = sq * (1.f/192.f) - m*m;
        statm[rowt*2] = m;
        statm[rowt*2+1] = rsqrtf(var + 1e-5f);
      }
    }
    float mr[4], rr[4];
    #pragma unroll
    for (int i = 0; i < 4; ++i) {
      int r = wv*16 + lq*4 + i;
      mr[i] = statm[r*2]; rr[i] = statm[r*2+1];
    }
    // ---- (e) fc1 GEMM ----
    f32x4 acc[12];
    #pragma unroll
    for (int nt = 0; nt < 12; ++nt) acc[nt] = zero4;
    #pragma unroll
    for (int ks = 0; ks < 6; ++ks) {
      bf16x8 a = *(const bf16x8*)(zg + rowt*200 + ks*32 + lq*8);
      #pragma unroll
      for (int nt = 0; nt < 12; ++nt)
        acc[nt] = __builtin_amdgcn_mfma_f32_16x16x32_bf16(a, f1v[(nt*6+ks)*64 + l], acc[nt], 0, 0, 0);
    }
    // ---- (f) LN-finish + gelu -> g ----
    #pragma unroll
    for (int nt = 0; nt < 12; ++nt) {
      #pragma unroll
      for (int i = 0; i < 4; ++i) {
        float hid = rr[i]*(acc[nt][i] - mr[i]*C1[nt]) + B1[nt];
        zg[(wv*16 + lq*4 + i)*200 + nt*16 + lr] = f2b(geluf(hid));
      }
    }
    // ---- (g) fc2 GEMM ----
    f32x4 a2[6];
    #pragma unroll
    for (int nt = 0; nt < 6; ++nt) a2[nt] = zero4;
    #pragma unroll
    for (int ks = 0; ks < 6; ++ks) {
      bf16x8 a = *(const bf16x8*)(zg + rowt*200 + ks*32 + lq*8);
      #pragma unroll
      for (int nt = 0; nt < 6; ++nt)
        a2[nt] = __builtin_amdgcn_mfma_f32_16x16x32_bf16(a, f2v[(nt*6+ks)*64 + l], a2[nt], 0, 0, 0);
    }
    // ---- (h) h update ----
    #pragma unroll
    for (int nt = 0; nt < 6; ++nt) {
      #pragma unroll
      for (int i = 0; i < 4; ++i) {
        int u = nt*4 + i;
        h[u] += a2[nt][i] + fb2[nt];
        hs[u] += h[u];
        hm[u] = fmaxf(hm[u], h[u]);
      }
    }
  }
  // ---- feat out ----
  #pragma unroll
  for (int nt = 0; nt < 6; ++nt) {
    #pragma unroll
    for (int i = 0; i < 4; ++i) {
      size_t r = ((size_t)blockIdx.x*128 + wv*16 + lq*4 + i)*288;
      int c = nt*16 + lr;
      feat[r + c] = f2b(h[nt*4+i]);
      feat[r + 96 + c] = f2b(hs[nt*4+i]*(1.f/7.f));
      feat[r + 192 + c] = f2b(hm[nt*4+i]);
    }
  }
}

// =================== K1b: static MLP -> s64/stats/base ===================
__global__ __launch_bounds__(512, 2) void k1b_static(
    const float* __restrict__ x_static, const float* __restrict__ sp2_w,
    const float* __restrict__ sp2_b, const float* __restrict__ base_w,
    const float* __restrict__ base_b, char* __restrict__ wsb,
    const unsigned short* __restrict__ feat)
{
  __shared__ unsigned short gh[128*136];
  const int tid = threadIdx.x;
  const int r4 = tid >> 2, p4 = tid & 3;
  const int s = blockIdx.x*128 + r4;

  float xv[64];
  {
    const float4* xp = (const float4*)(x_static + (size_t)s*64);
    #pragma unroll
    for (int q = 0; q < 16; ++q) *(float4*)&xv[q*4] = xp[q];
  }
  float sm = 0.f, sq = 0.f;
  #pragma unroll
  for (int k = 0; k < 64; ++k) { sm += xv[k]; sq = fmaf(xv[k], xv[k], sq); }
  const float ms = sm*(1.f/64.f);
  const float rs = rsqrtf(sq*(1.f/64.f) - ms*ms + 1e-5f);
  if (p4 == 0) {
    float bs = base_b[0];
    #pragma unroll
    for (int k = 0; k < 64; ++k) bs = fmaf(xv[k], base_w[k], bs);
    ((float*)(wsb + O_BASE))[s] = bs;
  }
  const float* sp1p = (const float*)(wsb + O_SP1P);
  const float* spC = (const float*)(wsb + O_SPC);
  const float* spB = (const float*)(wsb + O_SPB);
  float a1[32];
  #pragma unroll
  for (int u = 0; u < 32; ++u) a1[u] = 0.f;
  for (int k = 0; k < 64; ++k) {
    const float4* wr = (const float4*)(sp1p + k*128 + p4*32);
    float xk = xv[k];
    #pragma unroll
    for (int q = 0; q < 8; ++q) {
      float4 w = wr[q];
      a1[q*4+0] = fmaf(xk, w.x, a1[q*4+0]);
      a1[q*4+1] = fmaf(xk, w.y, a1[q*4+1]);
      a1[q*4+2] = fmaf(xk, w.z, a1[q*4+2]);
      a1[q*4+3] = fmaf(xk, w.w, a1[q*4+3]);
    }
  }
  #pragma unroll
  for (int u = 0; u < 16; ++u) {
    int j0 = p4*32 + 2*u;
    float g0 = geluf(rs*(a1[2*u]   - ms*spC[j0])   + spB[j0]);
    float g1 = geluf(rs*(a1[2*u+1] - ms*spC[j0+1]) + spB[j0+1]);
    *(unsigned*)(gh + r4*136 + j0) = (unsigned)f2b(g0) | ((unsigned)f2b(g1) << 16);
  }
  __syncthreads();
  float a2[16];
  #pragma unroll
  for (int u = 0; u < 16; ++u) a2[u] = sp2_b[p4*16+u];
  #pragma unroll 4
  for (int kk = 0; kk < 16; ++kk) {
    uint4 gw = *(const uint4*)(gh + r4*136 + kk*8);
    unsigned wb[4] = {gw.x, gw.y, gw.z, gw.w};
    #pragma unroll
    for (int e = 0; e < 4; ++e) {
      float gl = lo16(wb[e]), ghv = hi16(wb[e]);
      int k0 = kk*8 + 2*e;
      const float4* w0 = (const float4*)(sp2_w + k0*64 + p4*16);
      const float4* w1 = (const float4*)(sp2_w + (k0+1)*64 + p4*16);
      #pragma unroll
      for (int q = 0; q < 4; ++q) {
        float4 wa = w0[q], wbq = w1[q];
        a2[q*4+0] = fmaf(gl, wa.x, fmaf(ghv, wbq.x, a2[q*4+0]));
        a2[q*4+1] = fmaf(gl, wa.y, fmaf(ghv, wbq.y, a2[q*4+1]));
        a2[q*4+2] = fmaf(gl, wa.z, fmaf(ghv, wbq.z, a2[q*4+2]));
        a2[q*4+3] = fmaf(gl, wa.w, fmaf(ghv, wbq.w, a2[q*4+3]));
      }
    }
  }
  // round, store s64, accumulate stats (rounded values)
  float sm2 = 0.f, sq2 = 0.f;
  unsigned ow[8];
  #pragma unroll
  for (int u = 0; u < 8; ++u) {
    unsigned short r0 = f2b(a2[2*u]), r1 = f2b(a2[2*u+1]);
    ow[u] = (unsigned)r0 | ((unsigned)r1 << 16);
    float f0 = b2f(r0), f1 = b2f(r1);
    sm2 += f0 + f1; sq2 = fmaf(f0, f0, sq2); sq2 = fmaf(f1, f1, sq2);
  }
  {
    uint4* sp = (uint4*)((unsigned short*)(wsb + O_S64) + (size_t)s*64 + p4*16);
    sp[0] = make_uint4(ow[0], ow[1], ow[2], ow[3]);
    sp[1] = make_uint4(ow[4], ow[5], ow[6], ow[7]);
  }
  {
    const uint4* fr = (const uint4*)(feat + (size_t)s*288) + p4*9;
    #pragma unroll
    for (int q = 0; q < 9; ++q) {
      uint4 w = fr[q];
      unsigned wb[4] = {w.x, w.y, w.z, w.w};
      #pragma unroll
      for (int e = 0; e < 4; ++e) {
        float a = lo16(wb[e]), bb = hi16(wb[e]);
        sm2 += a + bb; sq2 = fmaf(a, a, sq2); sq2 = fmaf(bb, bb, sq2);
      }
    }
  }
  sm2 += __shfl_xor(sm2, 1, 64); sm2 += __shfl_xor(sm2, 2, 64);
  sq2 += __shfl_xor(sq2, 1, 64); sq2 += __shfl_xor(sq2, 2, 64);
  if (p4 == 0) {
    float m = sm2*(1.f/352.f);
    float var = sq2*(1.f/352.f) - m*m;
    float2 st; st.x = m; st.y = rsqrtf(var + 1e-5f);
    *(float2*)((float*)(wsb + O_STAT) + (size_t)s*2) = st;
  }
}

// =================== K2b: heads, weights resident in LDS ===================
// grid (86, 3): blockIdx.y = head; block stages its head's frags to LDS once,
// then loops over 256-sample chunks (8 waves x 32 rows, A-frags in regs).
__global__ __launch_bounds__(512, 2) void k2b_heads(
    const float* __restrict__ hm2_b, const float* __restrict__ hq2_b,
    const float* __restrict__ hn2_b, const char* __restrict__ wsb,
    const unsigned short* __restrict__ feat, float* __restrict__ out)
{
  extern __shared__ char smem[];
  const int g = blockIdx.y;
  const int tid = threadIdx.x;
  const int wv = tid >> 6, l = tid & 63, lr = l & 15, lq = l >> 4;
  const int ntn = (g == 2) ? 6 : 12;
  {
    const uint4* src = (const uint4*)(wsb + O_HDFR + (size_t)g*135168);
    uint4* dst = (uint4*)smem;
    const int n = ntn*11*64;
    for (int o = tid; o < n; o += 512) dst[o] = src[o];
  }
  __syncthreads();
  const bf16x8* wfr = (const bf16x8*)smem;
  const float* hdC = (const float*)(wsb + O_HDC);
  const float* hdB = (const float*)(wsb + O_HDBP);
  const float* w2c = (const float*)(wsb + O_W2C);
  const float* stat = (const float*)(wsb + O_STAT);
  const float* baseb = (const float*)(wsb + O_BASE);
  const unsigned short* s64p = (const unsigned short*)(wsb + O_S64);
  const float hb = (g == 0) ? hm2_b[0] : (g == 1) ? hq2_b[0] : hn2_b[0];
  const f32x4 zero4 = {0.f, 0.f, 0.f, 0.f};

  for (int c = blockIdx.x; c < 256; c += gridDim.x) {
    const int base = c*256 + wv*32;
    bf16x8 afr0[11], afr1[11];
    {
      const unsigned short* fr0 = feat + (size_t)(base + lr)*288;
      const unsigned short* fr1 = feat + (size_t)(base + 16 + lr)*288;
      #pragma unroll
      for (int ks = 0; ks < 9; ++ks) {
        afr0[ks] = *(const bf16x8*)(fr0 + ks*32 + lq*8);
        afr1[ks] = *(const bf16x8*)(fr1 + ks*32 + lq*8);
      }
      const unsigned short* sr0 = s64p + (size_t)(base + lr)*64;
      const unsigned short* sr1 = s64p + (size_t)(base + 16 + lr)*64;
      afr0[9]  = *(const bf16x8*)(sr0 + lq*8);
      afr0[10] = *(const bf16x8*)(sr0 + 32 + lq*8);
      afr1[9]  = *(const bf16x8*)(sr1 + lq*8);
      afr1[10] = *(const bf16x8*)(sr1 + 32 + lq*8);
    }
    float mr0[4], rr0[4], mr1[4], rr1[4];
    #pragma unroll
    for (int i = 0; i < 4; ++i) {
      float2 s0 = *(const float2*)(stat + (size_t)(base + lq*4 + i)*2);
      float2 s1 = *(const float2*)(stat + (size_t)(base + 16 + lq*4 + i)*2);
      mr0[i] = s0.x; rr0[i] = s0.y; mr1[i] = s1.x; rr1[i] = s1.y;
    }
    float pr0[4] = {0.f,0.f,0.f,0.f}, pr1[4] = {0.f,0.f,0.f,0.f};
    for (int nt = 0; nt < ntn; ++nt) {
      const int col = (g*12 + nt)*16 + lr;
      const float Cv = hdC[col], Bv = hdB[col], w2v = w2c[col];
      f32x4 a0 = zero4, a1v = zero4;
      #pragma unroll
      for (int ks = 0; ks < 11; ++ks) {
        bf16x8 b = wfr[(nt*11 + ks)*64 + l];
        a0  = __builtin_amdgcn_mfma_f32_16x16x32_bf16(afr0[ks], b, a0, 0, 0, 0);
        a1v = __builtin_amdgcn_mfma_f32_16x16x32_bf16(afr1[ks], b, a1v, 0, 0, 0);
      }
      #pragma unroll
      for (int i = 0; i < 4; ++i) {
        pr0[i] += geluf(rr0[i]*(a0[i]  - mr0[i]*Cv) + Bv) * w2v;
        pr1[i] += geluf(rr1[i]*(a1v[i] - mr1[i]*Cv) + Bv) * w2v;
      }
    }
    #pragma unroll
    for (int i = 0; i < 4; ++i) {
      float v0 = pr0[i], v1 = pr1[i];
      v0 += __shfl_xor(v0, 1, 64); v0 += __shfl_xor(v0, 2, 64);
      v0 += __shfl_xor(v0, 4, 64); v0 += __shfl_xor(v0, 8, 64);
      v1 += __shfl_xor(v1, 1, 64); v1 += __shfl_xor(v1, 2, 64);
      v1 += __shfl_xor(v1, 4, 64); v1 += __shfl_xor(v1, 8, 64);
      if (lr == 0) {
        int r0 = base + lq*4 + i;
        int r1 = base + 16 + lq*4 + i;
        float b0 = (g < 2) ? baseb[r0] : 0.f;
        float b1 = (g < 2) ? baseb[r1] : 0.f;
        out[(size_t)g*NB + r0] = b0 + hb + v0;
        out[(size_t)g*NB + r1] = b1 + hb + v1;
      }
    }
  }
}

extern "C" void kernel_launch(void* const* d_in, const int* in_sizes, int n_in,
                              void* d_out, int out_size, void* d_ws, size_t ws_size,
                              hipStream_t stream) {
  (void)in_sizes; (void)n_in; (void)out_size; (void)ws_size;
  const float* x_num    = (const float*)d_in[0];
  const float* x_static = (const float*)d_in[1];
  const int*   x_cat    = (const int*)  d_in[2];
  const float* cat_emb  = (const float*)d_in[3];
  const float* day_emb  = (const float*)d_in[4];
  const float* xproj_w  = (const float*)d_in[5];
  const float* xproj_b  = (const float*)d_in[6];
  const float* h0       = (const float*)d_in[7];
  const float* bln_g    = (const float*)d_in[8];
  const float* bln_b    = (const float*)d_in[9];
  const float* fc1_w    = (const float*)d_in[10];
  const float* fc1_b    = (const float*)d_in[11];
  const float* fc2_w    = (const float*)d_in[12];
  const float* fc2_b    = (const float*)d_in[13];
  const float* spln_g   = (const float*)d_in[14];
  const float* spln_b   = (const float*)d_in[15];
  const float* sp1_w    = (const float*)d_in[16];
  const float* sp1_b    = (const float*)d_in[17];
  const float* sp2_w    = (const float*)d_in[18];
  const float* sp2_b    = (const float*)d_in[19];
  const float* base_w   = (const float*)d_in[20];
  const float* base_b   = (const float*)d_in[21];
  const float* hln_g    = (const float*)d_in[22];
  const float* hln_b    = (const float*)d_in[23];
  const float* hm1_w    = (const float*)d_in[24];
  const float* hm1_b    = (const float*)d_in[25];
  const float* hm2_w    = (const float*)d_in[26];
  const float* hm2_b    = (const float*)d_in[27];
  const float* hq1_w    = (const float*)d_in[28];
  const float* hq1_b    = (const float*)d_in[29];
  const float* hq2_w    = (const float*)d_in[30];
  const float* hq2_b    = (const float*)d_in[31];
  const float* hn1_w    = (const float*)d_in[32];
  const float* hn1_b    = (const float*)d_in[33];
  const float* hn2_w    = (const float*)d_in[34];
  const float* hn2_b    = (const float*)d_in[35];

  char* wsb = (char*)d_ws;
  unsigned short* feat = (unsigned short*)(wsb + O_FEAT);
  float* out = (float*)d_out;

  k0_pre<<<2066, 512, 0, stream>>>(cat_emb, day_emb, xproj_w, xproj_b,
      bln_g, bln_b, fc1_w, fc1_b, fc2_w, spln_g, spln_b, sp1_w, sp1_b,
      hln_g, hln_b, hm1_w, hm1_b, hq1_w, hq1_b, hn1_w, hn1_b,
      hm2_w, hq2_w, hn2_w, wsb);
  k1_scan<<<512, 512, 162816, stream>>>(x_num, x_cat, h0, fc2_b, wsb, feat);
  k1b_static<<<512, 512, 0, stream>>>(x_static, sp2_w, sp2_b, base_w, base_b,
      wsb, feat);
  k2b_heads<<<dim3(86, 3), 512, 135168, stream>>>(hm2_b, hq2_b, hn2_b,
      wsb, feat, out);
}

// Round 4
// 409.313 us; speedup vs baseline: 25.1505x; 4.7980x over previous
//
#include <hip/hip_runtime.h>
#include <math.h>

#define NB 65536

typedef __attribute__((ext_vector_type(8))) short bf16x8;
typedef __attribute__((ext_vector_type(4))) float f32x4;

// ---- ws byte offsets ----
#define O_TAB2   0         // u16 [16][101][96]           310272
#define O_BIAST  310272    // f32 [7][96]                 2688
#define O_FC1C   312960    // f32 [192]                   768
#define O_FC1BP  313728    // f32 [192]                   768
#define O_FC1FR  314496    // u16 [72][64][8]             73728
#define O_FC2FR  388224    // u16 [36][64][8]             36864
#define O_XPFR   425088    // u16 [6][64][8]              6144
#define O_HDFR   431232    // u16 [330][64][8]            337920
#define O_HDC    769152    // f32 [480]                   1920
#define O_HDBP   771072    // f32 [480]                   1920
#define O_W2C    772992    // f32 [480]                   1920
#define O_SPC    807680    // f32 [128]                   512
#define O_SPB    808192    // f32 [128]                   512
#define O_FEAT   808960    // u16 [65536][288]            37748736
#define O_S64    38557696  // u16 [65536][64]             8388608
#define O_STAT   46946304  // f32 [65536][2]              524288
#define O_BASE   47470592  // f32 [65536]                 262144
#define O_SP1FR  47732736  // u16 [16][64][8]             16384
#define O_SP2FR  47749120  // u16 [16][64][8]             16384

__device__ __forceinline__ unsigned short f2b(float x) {
  unsigned int u = __float_as_uint(x);
  u += 0x7fffu + ((u >> 16) & 1u);   // RNE bf16
  return (unsigned short)(u >> 16);
}
__device__ __forceinline__ float b2f(unsigned short u) {
  return __uint_as_float(((unsigned)u) << 16);
}
__device__ __forceinline__ float lo16(unsigned w){ return __uint_as_float(w << 16); }
__device__ __forceinline__ float hi16(unsigned w){ return __uint_as_float(w & 0xffff0000u); }
__device__ __forceinline__ float geluf(float x) {
  return 0.5f * x * (1.0f + erff(x * 0.70710678118654752f));
}

// =================== K0: fold + frag-pack all weights ===================
__global__ void k0_pre(
    const float* __restrict__ cat_emb, const float* __restrict__ day_emb,
    const float* __restrict__ xproj_w, const float* __restrict__ xproj_b,
    const float* __restrict__ bln_g, const float* __restrict__ bln_b,
    const float* __restrict__ fc1_w, const float* __restrict__ fc1_b,
    const float* __restrict__ fc2_w,
    const float* __restrict__ spln_g, const float* __restrict__ spln_b,
    const float* __restrict__ sp1_w, const float* __restrict__ sp1_b,
    const float* __restrict__ sp2_w,
    const float* __restrict__ hln_g, const float* __restrict__ hln_b,
    const float* __restrict__ hm1_w, const float* __restrict__ hm1_b,
    const float* __restrict__ hq1_w, const float* __restrict__ hq1_b,
    const float* __restrict__ hn1_w, const float* __restrict__ hn1_b,
    const float* __restrict__ hm2_w, const float* __restrict__ hq2_w,
    const float* __restrict__ hn2_w,
    char* __restrict__ wsb)
{
  const int b = blockIdx.x, tid = threadIdx.x;
  if (b < 1616) {                     // pre-projected embedding table (bf16)
    if (tid < 96) {
      int c = b / 101, ix = b - c*101;
      float acc = 0.f;
      #pragma unroll
      for (int k = 0; k < 16; ++k)
        acc = fmaf(cat_emb[(c*101+ix)*16 + k], xproj_w[(32 + c*16 + k)*96 + tid], acc);
      ((unsigned short*)(wsb + O_TAB2))[(c*101+ix)*96 + tid] = f2b(acc);
    }
  } else if (b < 1623) {              // per-t bias (xproj_b + day part)
    if (tid < 96) {
      int t = b - 1616;
      float acc = xproj_b[tid];
      #pragma unroll
      for (int d = 0; d < 8; ++d)
        acc = fmaf(day_emb[(1+t)*8 + d], xproj_w[(288+d)*96 + tid], acc);
      ((float*)(wsb + O_BIAST))[t*96 + tid] = acc;
    }
  } else if (b < 1625) {              // fc1 LN-fold C / B'
    if (tid < 96) {
      int col = (b-1623)*96 + tid;
      float C = 0.f, Bp = fc1_b[col];
      for (int k = 0; k < 192; ++k) {
        float w = fc1_w[k*192 + col];
        C = fmaf(bln_g[k], w, C);
        Bp = fmaf(bln_b[k], w, Bp);
      }
      ((float*)(wsb + O_FC1C))[col] = C;
      ((float*)(wsb + O_FC1BP))[col] = Bp;
    }
  } else if (b < 1697) {              // fc1 frags [nt(12)][ks(6)]
    int seg = b - 1625, nt = seg / 6, ks = seg - nt*6;
    int ln = tid >> 3, j = tid & 7;
    int k = ks*32 + (ln>>4)*8 + j, col = nt*16 + (ln&15);
    ((unsigned short*)(wsb + O_FC1FR))[(seg*64 + ln)*8 + j] = f2b(bln_g[k]*fc1_w[k*192 + col]);
  } else if (b < 1733) {              // fc2 frags [nt(6)][ks(6)]
    int seg = b - 1697, nt = seg / 6, ks = seg - nt*6;
    int ln = tid >> 3, j = tid & 7;
    int k = ks*32 + (ln>>4)*8 + j, col = nt*16 + (ln&15);
    ((unsigned short*)(wsb + O_FC2FR))[(seg*64 + ln)*8 + j] = f2b(fc2_w[k*96 + col]);
  } else if (b < 1734) {              // xproj[0:32] frags [nt(6)]
    if (tid < 384) {
      int nt = tid >> 6, ln = tid & 63;
      int col = nt*16 + (ln&15);
      #pragma unroll
      for (int j = 0; j < 8; ++j) {
        int k = (ln>>4)*8 + j;
        ((unsigned short*)(wsb + O_XPFR))[(nt*64 + ln)*8 + j] = f2b(xproj_w[k*96 + col]);
      }
    }
  } else if (b < 2064) {              // head frags [nt(30)][ks(11)]
    int seg = b - 1734, nt = seg / 11, ks = seg - nt*11;
    int ln = tid >> 3, j = tid & 7;
    int k = ks*32 + (ln>>4)*8 + j, gcol = nt*16 + (ln&15);
    float w;
    if (gcol < 192) w = hm1_w[k*192 + gcol];
    else if (gcol < 384) w = hq1_w[k*192 + (gcol-192)];
    else w = hn1_w[k*96 + (gcol-384)];
    ((unsigned short*)(wsb + O_HDFR))[(seg*64 + ln)*8 + j] = f2b(hln_g[k]*w);
  } else if (b < 2065) {              // head C / B' / w2 concat
    if (tid < 480) {
      int gcol = tid;
      float C = 0.f, Bp, w2;
      if (gcol < 192) { Bp = hm1_b[gcol]; w2 = hm2_w[gcol]; }
      else if (gcol < 384) { Bp = hq1_b[gcol-192]; w2 = hq2_w[gcol-192]; }
      else { Bp = hn1_b[gcol-384]; w2 = hn2_w[gcol-384]; }
      for (int k = 0; k < 352; ++k) {
        float w;
        if (gcol < 192) w = hm1_w[k*192 + gcol];
        else if (gcol < 384) w = hq1_w[k*192 + (gcol-192)];
        else w = hn1_w[k*96 + (gcol-384)];
        C = fmaf(hln_g[k], w, C);
        Bp = fmaf(hln_b[k], w, Bp);
      }
      ((float*)(wsb + O_HDC))[gcol] = C;
      ((float*)(wsb + O_HDBP))[gcol] = Bp;
      ((float*)(wsb + O_W2C))[gcol] = w2;
    }
  } else if (b < 2066) {              // sp1 LN-fold (C from bf16-rounded weights)
    if (tid < 128) {
      int col = tid;
      float C = 0.f, Bp = sp1_b[col];
      for (int k = 0; k < 64; ++k) {
        float w = sp1_w[k*128 + col];
        C += b2f(f2b(spln_g[k]*w));
        Bp = fmaf(spln_b[k], w, Bp);
      }
      ((float*)(wsb + O_SPC))[col] = C;
      ((float*)(wsb + O_SPB))[col] = Bp;
    }
  } else if (b < 2082) {              // sp1 frags [nt(8)][ks(2)]
    int seg = b - 2066;
    int ln = tid >> 3, j = tid & 7;
    int nt = seg >> 1, ks = seg & 1;
    int k = ks*32 + (ln>>4)*8 + j, col = nt*16 + (ln&15);
    ((unsigned short*)(wsb + O_SP1FR))[(seg*64 + ln)*8 + j] = f2b(spln_g[k]*sp1_w[k*128 + col]);
  } else {                            // sp2 frags [nt(4)][ks(4)], b in [2082,2098)
    int seg = b - 2082;
    int ln = tid >> 3, j = tid & 7;
    int ks = seg & 3;
    int k = ks*32 + (ln>>4)*8 + j, col = (seg >> 2)*16 + (ln&15);
    ((unsigned short*)(wsb + O_SP2FR))[(seg*64 + ln)*8 + j] = f2b(sp2_w[k*64 + col]);
  }
}

// =================== K1: fused x-proj + 7-step MFMA recurrence ===================
__global__ __launch_bounds__(512, 2) void k1_scan(
    const float* __restrict__ x_num, const int* __restrict__ x_cat,
    const float* __restrict__ h0, const float* __restrict__ fc2_b,
    const char* __restrict__ wsb, unsigned short* __restrict__ feat,
    float* __restrict__ statg)
{
  extern __shared__ char smem[];
  unsigned short* zg = (unsigned short*)smem;              // 51200 B
  unsigned short* f1f = (unsigned short*)(smem + 51200);   // 73728 B
  unsigned short* f2f = (unsigned short*)(smem + 124928);  // 36864 B
  float* statm = (float*)(smem + 161792);                  // [128][2]

  const int tid = threadIdx.x;
  const int wv = tid >> 6;
  const int l = tid & 63;
  const int lr = l & 15;
  const int lq = l >> 4;
  const int rowt = wv*16 + lr;
  const long s_q = (long)blockIdx.x*128 + rowt;

  { // stage frag tables to LDS
    const uint4* s1 = (const uint4*)(wsb + O_FC1FR);
    uint4* d1 = (uint4*)f1f;
    for (int o = tid; o < 4608; o += 512) d1[o] = s1[o];
    const uint4* s2 = (const uint4*)(wsb + O_FC2FR);
    uint4* d2 = (uint4*)f2f;
    for (int o = tid; o < 2304; o += 512) d2[o] = s2[o];
  }
  bf16x8 xpf[6];
  {
    const bf16x8* xp = (const bf16x8*)(wsb + O_XPFR);
    #pragma unroll
    for (int nt = 0; nt < 6; ++nt) xpf[nt] = xp[nt*64 + l];
  }
  const float* biast = (const float*)(wsb + O_BIAST);
  const unsigned short* tab2 = (const unsigned short*)(wsb + O_TAB2);
  const bf16x8* f1v = (const bf16x8*)f1f;
  const bf16x8* f2v = (const bf16x8*)f2f;

  float C1[12], B1[12];
  {
    const float* fc1C = (const float*)(wsb + O_FC1C);
    const float* fc1BP = (const float*)(wsb + O_FC1BP);
    #pragma unroll
    for (int nt = 0; nt < 12; ++nt) { C1[nt] = fc1C[nt*16+lr]; B1[nt] = fc1BP[nt*16+lr]; }
  }
  float fb2[6];
  #pragma unroll
  for (int nt = 0; nt < 6; ++nt) fb2[nt] = fc2_b[nt*16+lr];

  float h[24], hs[24], hm[24];
  #pragma unroll
  for (int nt = 0; nt < 6; ++nt) {
    float v = h0[nt*16+lr];
    #pragma unroll
    for (int i = 0; i < 4; ++i) { h[nt*4+i] = v; hs[nt*4+i] = 0.f; hm[nt*4+i] = -3.4e38f; }
  }
  __syncthreads();

  const f32x4 zero4 = {0.f, 0.f, 0.f, 0.f};

  for (int t = 0; t < 7; ++t) {
    const long base_ct = s_q*7 + t;
    // ---- (a) embedding gather ----
    int idx[16];
    {
      const int4* ip = (const int4*)(x_cat + base_ct*16);
      int4 i0 = ip[0], i1 = ip[1], i2 = ip[2], i3 = ip[3];
      idx[0]=i0.x; idx[1]=i0.y; idx[2]=i0.z; idx[3]=i0.w;
      idx[4]=i1.x; idx[5]=i1.y; idx[6]=i1.z; idx[7]=i1.w;
      idx[8]=i2.x; idx[9]=i2.y; idx[10]=i2.z; idx[11]=i2.w;
      idx[12]=i3.x; idx[13]=i3.y; idx[14]=i3.z; idx[15]=i3.w;
    }
    float ga[24];
    #pragma unroll
    for (int u = 0; u < 24; ++u) ga[u] = 0.f;
    #pragma unroll
    for (int c = 0; c < 16; ++c) {
      const uint4* tp = (const uint4*)tab2 + (c*101 + idx[c])*12 + lq*3;
      uint4 w0 = tp[0], w1 = tp[1], w2 = tp[2];
      unsigned wb[12] = {w0.x,w0.y,w0.z,w0.w, w1.x,w1.y,w1.z,w1.w, w2.x,w2.y,w2.z,w2.w};
      #pragma unroll
      for (int q = 0; q < 12; ++q) { ga[2*q] += lo16(wb[q]); ga[2*q+1] += hi16(wb[q]); }
    }
    {
      unsigned ow[12];
      #pragma unroll
      for (int q = 0; q < 12; ++q)
        ow[q] = (unsigned)f2b(ga[2*q]) | ((unsigned)f2b(ga[2*q+1]) << 16);
      uint4* zp = (uint4*)(zg + rowt*200 + 96 + lq*24);
      zp[0] = make_uint4(ow[0],ow[1],ow[2],ow[3]);
      zp[1] = make_uint4(ow[4],ow[5],ow[6],ow[7]);
      zp[2] = make_uint4(ow[8],ow[9],ow[10],ow[11]);
    }
    // ---- (b) x_num @ xproj[0:32] via MFMA ----
    f32x4 xacc[6];
    {
      const float* xnp = x_num + base_ct*32 + lq*8;
      float xf[8];
      *(float4*)&xf[0] = *(const float4*)xnp;
      *(float4*)&xf[4] = *(const float4*)(xnp + 4);
      union { bf16x8 v; unsigned short u[8]; } au;
      #pragma unroll
      for (int j = 0; j < 8; ++j) au.u[j] = f2b(xf[j]);
      #pragma unroll
      for (int nt = 0; nt < 6; ++nt)
        xacc[nt] = __builtin_amdgcn_mfma_f32_16x16x32_bf16(au.v, xpf[nt], zero4, 0, 0, 0);
    }
    #pragma unroll
    for (int nt = 0; nt < 6; ++nt) {
      float bi = biast[t*96 + nt*16 + lr];
      #pragma unroll
      for (int i = 0; i < 4; ++i) {
        int zi = (wv*16 + lq*4 + i)*200 + 96 + nt*16 + lr;
        float v = b2f(zg[zi]) + xacc[nt][i] + bi;
        zg[zi] = f2b(v);
      }
    }
    // ---- (c) write h into zg h-half ----
    #pragma unroll
    for (int nt = 0; nt < 6; ++nt) {
      #pragma unroll
      for (int i = 0; i < 4; ++i)
        zg[(wv*16 + lq*4 + i)*200 + nt*16 + lr] = f2b(h[nt*4+i]);
    }
    // ---- (d) LN stats ----
    {
      float sm = 0.f, sq = 0.f;
      #pragma unroll
      for (int q6 = 0; q6 < 6; ++q6) {
        uint4 w = *(const uint4*)(zg + rowt*200 + lq*48 + q6*8);
        unsigned wb[4] = {w.x, w.y, w.z, w.w};
        #pragma unroll
        for (int e = 0; e < 4; ++e) {
          float a = lo16(wb[e]), bb = hi16(wb[e]);
          sm += a + bb; sq = fmaf(a, a, sq); sq = fmaf(bb, bb, sq);
        }
      }
      sm += __shfl_xor(sm, 16, 64); sm += __shfl_xor(sm, 32, 64);
      sq += __shfl_xor(sq, 16, 64); sq += __shfl_xor(sq, 32, 64);
      if (lq == 0) {
        float m = sm * (1.f/192.f);
        float var = sq * (1.f/192.f) - m*m;
        statm[rowt*2] = m;
        statm[rowt*2+1] = rsqrtf(var + 1e-5f);
      }
    }
    float mr[4], rr[4];
    #pragma unroll
    for (int i = 0; i < 4; ++i) {
      int r = wv*16 + lq*4 + i;
      mr[i] = statm[r*2]; rr[i] = statm[r*2+1];
    }
    // ---- (e) fc1 GEMM ----
    f32x4 acc[12];
    #pragma unroll
    for (int nt = 0; nt < 12; ++nt) acc[nt] = zero4;
    #pragma unroll
    for (int ks = 0; ks < 6; ++ks) {
      bf16x8 a = *(const bf16x8*)(zg + rowt*200 + ks*32 + lq*8);
      #pragma unroll
      for (int nt = 0; nt < 12; ++nt)
        acc[nt] = __builtin_amdgcn_mfma_f32_16x16x32_bf16(a, f1v[(nt*6+ks)*64 + l], acc[nt], 0, 0, 0);
    }
    // ---- (f) LN-finish + gelu -> g ----
    #pragma unroll
    for (int nt = 0; nt < 12; ++nt) {
      #pragma unroll
      for (int i = 0; i < 4; ++i) {
        float hid = rr[i]*(acc[nt][i] - mr[i]*C1[nt]) + B1[nt];
        zg[(wv*16 + lq*4 + i)*200 + nt*16 + lr] = f2b(geluf(hid));
      }
    }
    // ---- (g) fc2 GEMM ----
    f32x4 a2[6];
    #pragma unroll
    for (int nt = 0; nt < 6; ++nt) a2[nt] = zero4;
    #pragma unroll
    for (int ks = 0; ks < 6; ++ks) {
      bf16x8 a = *(const bf16x8*)(zg + rowt*200 + ks*32 + lq*8);
      #pragma unroll
      for (int nt = 0; nt < 6; ++nt)
        a2[nt] = __builtin_amdgcn_mfma_f32_16x16x32_bf16(a, f2v[(nt*6+ks)*64 + l], a2[nt], 0, 0, 0);
    }
    // ---- (h) h update ----
    #pragma unroll
    for (int nt = 0; nt < 6; ++nt) {
      #pragma unroll
      for (int i = 0; i < 4; ++i) {
        int u = nt*4 + i;
        h[u] += a2[nt][i] + fb2[nt];
        hs[u] += h[u];
        hm[u] = fmaxf(hm[u], h[u]);
      }
    }
  }
  // ---- feat out + partial z-stats (sum/sumsq of the 288 rounded values) ----
  float st[4] = {0.f,0.f,0.f,0.f}, qt[4] = {0.f,0.f,0.f,0.f};
  #pragma unroll
  for (int nt = 0; nt < 6; ++nt) {
    #pragma unroll
    for (int i = 0; i < 4; ++i) {
      size_t r = ((size_t)blockIdx.x*128 + wv*16 + lq*4 + i)*288;
      int c = nt*16 + lr;
      unsigned short b0 = f2b(h[nt*4+i]);
      unsigned short b1 = f2b(hs[nt*4+i]*(1.f/7.f));
      unsigned short b2v = f2b(hm[nt*4+i]);
      feat[r + c] = b0;
      feat[r + 96 + c] = b1;
      feat[r + 192 + c] = b2v;
      float f0 = b2f(b0), f1 = b2f(b1), f2v = b2f(b2v);
      st[i] += f0 + f1 + f2v;
      qt[i] = fmaf(f0, f0, fmaf(f1, f1, fmaf(f2v, f2v, qt[i])));
    }
  }
  #pragma unroll
  for (int i = 0; i < 4; ++i) {
    st[i] += __shfl_xor(st[i], 1, 64); st[i] += __shfl_xor(st[i], 2, 64);
    st[i] += __shfl_xor(st[i], 4, 64); st[i] += __shfl_xor(st[i], 8, 64);
    qt[i] += __shfl_xor(qt[i], 1, 64); qt[i] += __shfl_xor(qt[i], 2, 64);
    qt[i] += __shfl_xor(qt[i], 4, 64); qt[i] += __shfl_xor(qt[i], 8, 64);
  }
  if (lr == 0) {
    #pragma unroll
    for (int i = 0; i < 4; ++i) {
      size_t r = (size_t)blockIdx.x*128 + wv*16 + lq*4 + i;
      float2 o; o.x = st[i]; o.y = qt[i];
      *(float2*)(statg + r*2) = o;
    }
  }
}

// =================== K1b: static MLP via MFMA -> s64/stats/base ===================
// 8 waves x 16 samples; frags in LDS; no runtime-indexed register arrays.
__global__ __launch_bounds__(512, 2) void k1b_static(
    const float* __restrict__ x_static, const float* __restrict__ sp2_b,
    const float* __restrict__ base_w, const float* __restrict__ base_b,
    char* __restrict__ wsb)
{
  __shared__ char smem[68608];
  unsigned short* sp1f = (unsigned short*)smem;            // 16384
  unsigned short* sp2f = (unsigned short*)(smem + 16384);  // 16384
  unsigned short* hid  = (unsigned short*)(smem + 32768);  // 8 waves * 16*136*2 = 34816

  const int tid = threadIdx.x;
  const int wv = tid >> 6, l = tid & 63, lr = l & 15, lq = l >> 4;
  const int srow = blockIdx.x*128 + wv*16;

  { // stage frag tables
    const uint4* s1 = (const uint4*)(wsb + O_SP1FR);
    uint4* d1 = (uint4*)sp1f;
    for (int o = tid; o < 1024; o += 512) d1[o] = s1[o];
    const uint4* s2 = (const uint4*)(wsb + O_SP2FR);
    uint4* d2 = (uint4*)sp2f;
    for (int o = tid; o < 1024; o += 512) d2[o] = s2[o];
  }
  __syncthreads();

  // ---- load raw x_static row (lane owns row lr, cols lq*8.. and 32+lq*8..) ----
  float x0f[8], x1f[8];
  {
    const float* xr = x_static + (size_t)(srow + lr)*64;
    *(float4*)&x0f[0] = *(const float4*)(xr + lq*8);
    *(float4*)&x0f[4] = *(const float4*)(xr + lq*8 + 4);
    *(float4*)&x1f[0] = *(const float4*)(xr + 32 + lq*8);
    *(float4*)&x1f[4] = *(const float4*)(xr + 32 + lq*8 + 4);
  }
  // ---- LN stats + base over raw fp32 ----
  float sm = 0.f, sq = 0.f, bp = 0.f;
  #pragma unroll
  for (int j = 0; j < 8; ++j) {
    sm += x0f[j] + x1f[j];
    sq = fmaf(x0f[j], x0f[j], fmaf(x1f[j], x1f[j], sq));
    bp = fmaf(x0f[j], base_w[lq*8 + j], fmaf(x1f[j], base_w[32 + lq*8 + j], bp));
  }
  sm += __shfl_xor(sm, 16, 64); sm += __shfl_xor(sm, 32, 64);
  sq += __shfl_xor(sq, 16, 64); sq += __shfl_xor(sq, 32, 64);
  bp += __shfl_xor(bp, 16, 64); bp += __shfl_xor(bp, 32, 64);
  if (lq == 0) ((float*)(wsb + O_BASE))[srow + lr] = bp + base_b[0];
  const float ms = sm*(1.f/64.f);
  const float rs = rsqrtf(sq*(1.f/64.f) - ms*ms + 1e-5f);
  // redistribute stats to C-layout rows (row lq*4+i lives in lane lr==lq*4+i)
  float mr[4], rr[4];
  #pragma unroll
  for (int i = 0; i < 4; ++i) {
    mr[i] = __shfl(ms, lq*4 + i, 16);
    rr[i] = __shfl(rs, lq*4 + i, 16);
  }
  // ---- A-frags (raw xs, bf16) ----
  union { bf16x8 v; unsigned short u[8]; } ua0, ua1;
  #pragma unroll
  for (int j = 0; j < 8; ++j) { ua0.u[j] = f2b(x0f[j]); ua1.u[j] = f2b(x1f[j]); }

  const f32x4 zero4 = {0.f, 0.f, 0.f, 0.f};
  const bf16x8* f1 = (const bf16x8*)sp1f;
  const bf16x8* f2 = (const bf16x8*)sp2f;
  unsigned short* hw = hid + wv*2176;   // wave-private [16][136]

  // ---- stage 1: [16x64] @ [64x128] ----
  f32x4 acc[8];
  #pragma unroll
  for (int nt = 0; nt < 8; ++nt) acc[nt] = zero4;
  #pragma unroll
  for (int nt = 0; nt < 8; ++nt) {
    acc[nt] = __builtin_amdgcn_mfma_f32_16x16x32_bf16(ua0.v, f1[(nt*2 + 0)*64 + l], acc[nt], 0, 0, 0);
    acc[nt] = __builtin_amdgcn_mfma_f32_16x16x32_bf16(ua1.v, f1[(nt*2 + 1)*64 + l], acc[nt], 0, 0, 0);
  }
  // ---- LN-fix + gelu -> hid LDS (transpose via C-layout scatter) ----
  {
    const float* spC = (const float*)(wsb + O_SPC);
    const float* spB = (const float*)(wsb + O_SPB);
    #pragma unroll
    for (int nt = 0; nt < 8; ++nt) {
      float Cv = spC[nt*16 + lr], Bv = spB[nt*16 + lr];
      #pragma unroll
      for (int i = 0; i < 4; ++i) {
        float hv = rr[i]*(acc[nt][i] - mr[i]*Cv) + Bv;
        hw[(lq*4 + i)*136 + nt*16 + lr] = f2b(geluf(hv));
      }
    }
  }
  // ---- stage 2: [16x128] @ [128x64] ----
  f32x4 a2[4];
  #pragma unroll
  for (int nt = 0; nt < 4; ++nt) a2[nt] = zero4;
  #pragma unroll
  for (int ks = 0; ks < 4; ++ks) {
    bf16x8 a = *(const bf16x8*)(hw + lr*136 + ks*32 + lq*8);
    #pragma unroll
    for (int nt = 0; nt < 4; ++nt)
      a2[nt] = __builtin_amdgcn_mfma_f32_16x16x32_bf16(a, f2[(nt*4 + ks)*64 + l], a2[nt], 0, 0, 0);
  }
  // ---- s64 out + finalize z-LN stats ----
  float ss[4] = {0.f,0.f,0.f,0.f}, qq[4] = {0.f,0.f,0.f,0.f};
  {
    unsigned short* s64p = (unsigned short*)(wsb + O_S64);
    #pragma unroll
    for (int nt = 0; nt < 4; ++nt) {
      float bv = sp2_b[nt*16 + lr];
      #pragma unroll
      for (int i = 0; i < 4; ++i) {
        unsigned short rb = f2b(a2[nt][i] + bv);
        s64p[(size_t)(srow + lq*4 + i)*64 + nt*16 + lr] = rb;
        float f = b2f(rb);
        ss[i] += f; qq[i] = fmaf(f, f, qq[i]);
      }
    }
  }
  #pragma unroll
  for (int i = 0; i < 4; ++i) {
    ss[i] += __shfl_xor(ss[i], 1, 64); ss[i] += __shfl_xor(ss[i], 2, 64);
    ss[i] += __shfl_xor(ss[i], 4, 64); ss[i] += __shfl_xor(ss[i], 8, 64);
    qq[i] += __shfl_xor(qq[i], 1, 64); qq[i] += __shfl_xor(qq[i], 2, 64);
    qq[i] += __shfl_xor(qq[i], 4, 64); qq[i] += __shfl_xor(qq[i], 8, 64);
  }
  if (lr == 0) {
    float* stat = (float*)(wsb + O_STAT);
    #pragma unroll
    for (int i = 0; i < 4; ++i) {
      size_t r = (size_t)srow + lq*4 + i;
      float2 fs = *(float2*)(stat + r*2);
      float stot = fs.x + ss[i], qtot = fs.y + qq[i];
      float m = stot*(1.f/352.f);
      float var = qtot*(1.f/352.f) - m*m;
      float2 o; o.x = m; o.y = rsqrtf(var + 1e-5f);
      *(float2*)(stat + r*2) = o;
    }
  }
}

// =================== K2b: heads, weights resident in LDS ===================
__global__ __launch_bounds__(512, 2) void k2b_heads(
    const float* __restrict__ hm2_b, const float* __restrict__ hq2_b,
    const float* __restrict__ hn2_b, const char* __restrict__ wsb,
    const unsigned short* __restrict__ feat, float* __restrict__ out)
{
  extern __shared__ char smem[];
  const int g = blockIdx.y;
  const int tid = threadIdx.x;
  const int wv = tid >> 6, l = tid & 63, lr = l & 15, lq = l >> 4;
  const int ntn = (g == 2) ? 6 : 12;
  {
    const uint4* src = (const uint4*)(wsb + O_HDFR + (size_t)g*135168);
    uint4* dst = (uint4*)smem;
    const int n = ntn*11*64;
    for (int o = tid; o < n; o += 512) dst[o] = src[o];
  }
  __syncthreads();
  const bf16x8* wfr = (const bf16x8*)smem;
  const float* hdC = (const float*)(wsb + O_HDC);
  const float* hdB = (const float*)(wsb + O_HDBP);
  const float* w2c = (const float*)(wsb + O_W2C);
  const float* stat = (const float*)(wsb + O_STAT);
  const float* baseb = (const float*)(wsb + O_BASE);
  const unsigned short* s64p = (const unsigned short*)(wsb + O_S64);
  const float hb = (g == 0) ? hm2_b[0] : (g == 1) ? hq2_b[0] : hn2_b[0];
  const f32x4 zero4 = {0.f, 0.f, 0.f, 0.f};

  for (int c = blockIdx.x; c < 256; c += gridDim.x) {
    const int base = c*256 + wv*32;
    bf16x8 afr0[11], afr1[11];
    {
      const unsigned short* fr0 = feat + (size_t)(base + lr)*288;
      const unsigned short* fr1 = feat + (size_t)(base + 16 + lr)*288;
      #pragma unroll
      for (int ks = 0; ks < 9; ++ks) {
        afr0[ks] = *(const bf16x8*)(fr0 + ks*32 + lq*8);
        afr1[ks] = *(const bf16x8*)(fr1 + ks*32 + lq*8);
      }
      const unsigned short* sr0 = s64p + (size_t)(base + lr)*64;
      const unsigned short* sr1 = s64p + (size_t)(base + 16 + lr)*64;
      afr0[9]  = *(const bf16x8*)(sr0 + lq*8);
      afr0[10] = *(const bf16x8*)(sr0 + 32 + lq*8);
      afr1[9]  = *(const bf16x8*)(sr1 + lq*8);
      afr1[10] = *(const bf16x8*)(sr1 + 32 + lq*8);
    }
    float mr0[4], rr0[4], mr1[4], rr1[4];
    #pragma unroll
    for (int i = 0; i < 4; ++i) {
      float2 s0 = *(const float2*)(stat + (size_t)(base + lq*4 + i)*2);
      float2 s1 = *(const float2*)(stat + (size_t)(base + 16 + lq*4 + i)*2);
      mr0[i] = s0.x; rr0[i] = s0.y; mr1[i] = s1.x; rr1[i] = s1.y;
    }
    float pr0[4] = {0.f,0.f,0.f,0.f}, pr1[4] = {0.f,0.f,0.f,0.f};
    for (int nt = 0; nt < ntn; ++nt) {
      const int col = (g*12 + nt)*16 + lr;
      const float Cv = hdC[col], Bv = hdB[col], w2v = w2c[col];
      f32x4 a0 = zero4, a1v = zero4;
      #pragma unroll
      for (int ks = 0; ks < 11; ++ks) {
        bf16x8 b = wfr[(nt*11 + ks)*64 + l];
        a0  = __builtin_amdgcn_mfma_f32_16x16x32_bf16(afr0[ks], b, a0, 0, 0, 0);
        a1v = __builtin_amdgcn_mfma_f32_16x16x32_bf16(afr1[ks], b, a1v, 0, 0, 0);
      }
      #pragma unroll
      for (int i = 0; i < 4; ++i) {
        pr0[i] += geluf(rr0[i]*(a0[i]  - mr0[i]*Cv) + Bv) * w2v;
        pr1[i] += geluf(rr1[i]*(a1v[i] - mr1[i]*Cv) + Bv) * w2v;
      }
    }
    #pragma unroll
    for (int i = 0; i < 4; ++i) {
      float v0 = pr0[i], v1 = pr1[i];
      v0 += __shfl_xor(v0, 1, 64); v0 += __shfl_xor(v0, 2, 64);
      v0 += __shfl_xor(v0, 4, 64); v0 += __shfl_xor(v0, 8, 64);
      v1 += __shfl_xor(v1, 1, 64); v1 += __shfl_xor(v1, 2, 64);
      v1 += __shfl_xor(v1, 4, 64); v1 += __shfl_xor(v1, 8, 64);
      if (lr == 0) {
        int r0 = base + lq*4 + i;
        int r1 = base + 16 + lq*4 + i;
        float b0 = (g < 2) ? baseb[r0] : 0.f;
        float b1 = (g < 2) ? baseb[r1] : 0.f;
        out[(size_t)g*NB + r0] = b0 + hb + v0;
        out[(size_t)g*NB + r1] = b1 + hb + v1;
      }
    }
  }
}

extern "C" void kernel_launch(void* const* d_in, const int* in_sizes, int n_in,
                              void* d_out, int out_size, void* d_ws, size_t ws_size,
                              hipStream_t stream) {
  (void)in_sizes; (void)n_in; (void)out_size; (void)ws_size;
  const float* x_num    = (const float*)d_in[0];
  const float* x_static = (const float*)d_in[1];
  const int*   x_cat    = (const int*)  d_in[2];
  const float* cat_emb  = (const float*)d_in[3];
  const float* day_emb  = (const float*)d_in[4];
  const float* xproj_w  = (const float*)d_in[5];
  const float* xproj_b  = (const float*)d_in[6];
  const float* h0       = (const float*)d_in[7];
  const float* bln_g    = (const float*)d_in[8];
  const float* bln_b    = (const float*)d_in[9];
  const float* fc1_w    = (const float*)d_in[10];
  const float* fc1_b    = (const float*)d_in[11];
  const float* fc2_w    = (const float*)d_in[12];
  const float* fc2_b    = (const float*)d_in[13];
  const float* spln_g   = (const float*)d_in[14];
  const float* spln_b   = (const float*)d_in[15];
  const float* sp1_w    = (const float*)d_in[16];
  const float* sp1_b    = (const float*)d_in[17];
  const float* sp2_w    = (const float*)d_in[18];
  const float* sp2_b    = (const float*)d_in[19];
  const float* base_w   = (const float*)d_in[20];
  const float* base_b   = (const float*)d_in[21];
  const float* hln_g    = (const float*)d_in[22];
  const float* hln_b    = (const float*)d_in[23];
  const float* hm1_w    = (const float*)d_in[24];
  const float* hm1_b    = (const float*)d_in[25];
  const float* hm2_w    = (const float*)d_in[26];
  const float* hm2_b    = (const float*)d_in[27];
  const float* hq1_w    = (const float*)d_in[28];
  const float* hq1_b    = (const float*)d_in[29];
  const float* hq2_w    = (const float*)d_in[30];
  const float* hq2_b    = (const float*)d_in[31];
  const float* hn1_w    = (const float*)d_in[32];
  const float* hn1_b    = (const float*)d_in[33];
  const float* hn2_w    = (const float*)d_in[34];
  const float* hn2_b    = (const float*)d_in[35];

  char* wsb = (char*)d_ws;
  unsigned short* feat = (unsigned short*)(wsb + O_FEAT);
  float* statg = (float*)(wsb + O_STAT);
  float* out = (float*)d_out;

  k0_pre<<<2098, 512, 0, stream>>>(cat_emb, day_emb, xproj_w, xproj_b,
      bln_g, bln_b, fc1_w, fc1_b, fc2_w, spln_g, spln_b, sp1_w, sp1_b, sp2_w,
      hln_g, hln_b, hm1_w, hm1_b, hq1_w, hq1_b, hn1_w, hn1_b,
      hm2_w, hq2_w, hn2_w, wsb);
  k1_scan<<<512, 512, 162816, stream>>>(x_num, x_cat, h0, fc2_b, wsb, feat, statg);
  k1b_static<<<512, 512, 0, stream>>>(x_static, sp2_b, base_w, base_b, wsb);
  k2b_heads<<<dim3(86, 3), 512, 135168, stream>>>(hm2_b, hq2_b, hn2_b,
      wsb, feat, out);
}

// Round 5
// 381.827 us; speedup vs baseline: 26.9609x; 1.0720x over previous
//
#include <hip/hip_runtime.h>
#include <math.h>

#define NB 65536

typedef __attribute__((ext_vector_type(8))) short bf16x8;
typedef __attribute__((ext_vector_type(4))) float f32x4;

// ---- ws byte offsets ----
#define O_TAB2   0         // u16 [16][101][96]           310272
#define O_BIAST  310272    // f32 [7][96]                 2688
#define O_FC1C   312960    // f32 [192]                   768
#define O_FC1BP  313728    // f32 [192]                   768
#define O_FC1FR  314496    // u16 [72][64][8]             73728
#define O_FC2FR  388224    // u16 [36][64][8]             36864
#define O_XPFR   425088    // u16 [6][64][8]              6144
#define O_HDFR   431232    // u16 [330][64][8]            337920
#define O_HDC    769152    // f32 [480]                   1920
#define O_HDBP   771072    // f32 [480]                   1920
#define O_W2C    772992    // f32 [480]                   1920
#define O_SPC    807680    // f32 [128]                   512
#define O_SPB    808192    // f32 [128]                   512
#define O_FEAT   808960    // u16 [65536][288]            37748736
#define O_S64    38557696  // u16 [65536][64]             8388608
#define O_STAT   46946304  // f32 [65536][2]              524288
#define O_BASE   47470592  // f32 [65536]                 262144
#define O_SP1FR  47732736  // u16 [16][64][8]             16384
#define O_SP2FR  47749120  // u16 [16][64][8]             16384
#define O_XROW   47765504  // u16 [65536*7][96]           88080384
#define O_XSTAT  135845888 // f32 [65536*7][2]            3670016

__device__ __forceinline__ unsigned short f2b(float x) {
  unsigned int u = __float_as_uint(x);
  u += 0x7fffu + ((u >> 16) & 1u);   // RNE bf16
  return (unsigned short)(u >> 16);
}
__device__ __forceinline__ float b2f(unsigned short u) {
  return __uint_as_float(((unsigned)u) << 16);
}
__device__ __forceinline__ float lo16(unsigned w){ return __uint_as_float(w << 16); }
__device__ __forceinline__ float hi16(unsigned w){ return __uint_as_float(w & 0xffff0000u); }
__device__ __forceinline__ float geluf(float x) {
  return 0.5f * x * (1.0f + erff(x * 0.70710678118654752f));
}

// =================== K0: fold + frag-pack all weights ===================
__global__ void k0_pre(
    const float* __restrict__ cat_emb, const float* __restrict__ day_emb,
    const float* __restrict__ xproj_w, const float* __restrict__ xproj_b,
    const float* __restrict__ bln_g, const float* __restrict__ bln_b,
    const float* __restrict__ fc1_w, const float* __restrict__ fc1_b,
    const float* __restrict__ fc2_w,
    const float* __restrict__ spln_g, const float* __restrict__ spln_b,
    const float* __restrict__ sp1_w, const float* __restrict__ sp1_b,
    const float* __restrict__ sp2_w,
    const float* __restrict__ hln_g, const float* __restrict__ hln_b,
    const float* __restrict__ hm1_w, const float* __restrict__ hm1_b,
    const float* __restrict__ hq1_w, const float* __restrict__ hq1_b,
    const float* __restrict__ hn1_w, const float* __restrict__ hn1_b,
    const float* __restrict__ hm2_w, const float* __restrict__ hq2_w,
    const float* __restrict__ hn2_w,
    char* __restrict__ wsb)
{
  const int b = blockIdx.x, tid = threadIdx.x;
  if (b < 1616) {                     // pre-projected embedding table (bf16)
    if (tid < 96) {
      int c = b / 101, ix = b - c*101;
      float acc = 0.f;
      #pragma unroll
      for (int k = 0; k < 16; ++k)
        acc = fmaf(cat_emb[(c*101+ix)*16 + k], xproj_w[(32 + c*16 + k)*96 + tid], acc);
      ((unsigned short*)(wsb + O_TAB2))[(c*101+ix)*96 + tid] = f2b(acc);
    }
  } else if (b < 1623) {              // per-t bias (xproj_b + day part)
    if (tid < 96) {
      int t = b - 1616;
      float acc = xproj_b[tid];
      #pragma unroll
      for (int d = 0; d < 8; ++d)
        acc = fmaf(day_emb[(1+t)*8 + d], xproj_w[(288+d)*96 + tid], acc);
      ((float*)(wsb + O_BIAST))[t*96 + tid] = acc;
    }
  } else if (b < 1625) {              // fc1 LN-fold C / B'
    if (tid < 96) {
      int col = (b-1623)*96 + tid;
      float C = 0.f, Bp = fc1_b[col];
      for (int k = 0; k < 192; ++k) {
        float w = fc1_w[k*192 + col];
        C = fmaf(bln_g[k], w, C);
        Bp = fmaf(bln_b[k], w, Bp);
      }
      ((float*)(wsb + O_FC1C))[col] = C;
      ((float*)(wsb + O_FC1BP))[col] = Bp;
    }
  } else if (b < 1697) {              // fc1 frags [nt(12)][ks(6)]
    int seg = b - 1625, nt = seg / 6, ks = seg - nt*6;
    int ln = tid >> 3, j = tid & 7;
    int k = ks*32 + (ln>>4)*8 + j, col = nt*16 + (ln&15);
    ((unsigned short*)(wsb + O_FC1FR))[(seg*64 + ln)*8 + j] = f2b(bln_g[k]*fc1_w[k*192 + col]);
  } else if (b < 1733) {              // fc2 frags [nt(6)][ks(6)]
    int seg = b - 1697, nt = seg / 6, ks = seg - nt*6;
    int ln = tid >> 3, j = tid & 7;
    int k = ks*32 + (ln>>4)*8 + j, col = nt*16 + (ln&15);
    ((unsigned short*)(wsb + O_FC2FR))[(seg*64 + ln)*8 + j] = f2b(fc2_w[k*96 + col]);
  } else if (b < 1734) {              // xproj[0:32] frags [nt(6)]
    if (tid < 384) {
      int nt = tid >> 6, ln = tid & 63;
      int col = nt*16 + (ln&15);
      #pragma unroll
      for (int j = 0; j < 8; ++j) {
        int k = (ln>>4)*8 + j;
        ((unsigned short*)(wsb + O_XPFR))[(nt*64 + ln)*8 + j] = f2b(xproj_w[k*96 + col]);
      }
    }
  } else if (b < 2064) {              // head frags [nt(30)][ks(11)]
    int seg = b - 1734, nt = seg / 11, ks = seg - nt*11;
    int ln = tid >> 3, j = tid & 7;
    int k = ks*32 + (ln>>4)*8 + j, gcol = nt*16 + (ln&15);
    float w;
    if (gcol < 192) w = hm1_w[k*192 + gcol];
    else if (gcol < 384) w = hq1_w[k*192 + (gcol-192)];
    else w = hn1_w[k*96 + (gcol-384)];
    ((unsigned short*)(wsb + O_HDFR))[(seg*64 + ln)*8 + j] = f2b(hln_g[k]*w);
  } else if (b < 2065) {              // head C / B' / w2 concat
    if (tid < 480) {
      int gcol = tid;
      float C = 0.f, Bp, w2;
      if (gcol < 192) { Bp = hm1_b[gcol]; w2 = hm2_w[gcol]; }
      else if (gcol < 384) { Bp = hq1_b[gcol-192]; w2 = hq2_w[gcol-192]; }
      else { Bp = hn1_b[gcol-384]; w2 = hn2_w[gcol-384]; }
      for (int k = 0; k < 352; ++k) {
        float w;
        if (gcol < 192) w = hm1_w[k*192 + gcol];
        else if (gcol < 384) w = hq1_w[k*192 + (gcol-192)];
        else w = hn1_w[k*96 + (gcol-384)];
        C = fmaf(hln_g[k], w, C);
        Bp = fmaf(hln_b[k], w, Bp);
      }
      ((float*)(wsb + O_HDC))[gcol] = C;
      ((float*)(wsb + O_HDBP))[gcol] = Bp;
      ((float*)(wsb + O_W2C))[gcol] = w2;
    }
  } else if (b < 2066) {              // sp1 LN-fold (C from bf16-rounded weights)
    if (tid < 128) {
      int col = tid;
      float C = 0.f, Bp = sp1_b[col];
      for (int k = 0; k < 64; ++k) {
        float w = sp1_w[k*128 + col];
        C += b2f(f2b(spln_g[k]*w));
        Bp = fmaf(spln_b[k], w, Bp);
      }
      ((float*)(wsb + O_SPC))[col] = C;
      ((float*)(wsb + O_SPB))[col] = Bp;
    }
  } else if (b < 2082) {              // sp1 frags [nt(8)][ks(2)]
    int seg = b - 2066;
    int ln = tid >> 3, j = tid & 7;
    int nt = seg >> 1, ks = seg & 1;
    int k = ks*32 + (ln>>4)*8 + j, col = nt*16 + (ln&15);
    ((unsigned short*)(wsb + O_SP1FR))[(seg*64 + ln)*8 + j] = f2b(spln_g[k]*sp1_w[k*128 + col]);
  } else {                            // sp2 frags [nt(4)][ks(4)], b in [2082,2098)
    int seg = b - 2082;
    int ln = tid >> 3, j = tid & 7;
    int ks = seg & 3;
    int k = ks*32 + (ln>>4)*8 + j, col = (seg >> 2)*16 + (ln&15);
    ((unsigned short*)(wsb + O_SP2FR))[(seg*64 + ln)*8 + j] = f2b(sp2_w[k*64 + col]);
  }
}

// =================== K1a: x-projection (gather + x_num MFMA) ===================
// 256 thr = 4 waves, 64 samples/block, 7 t's. High occupancy hides gather latency.
// Writes x rows (bf16) + per-(s,t) LN partial stats (sum, sumsq of rounded vals).
__global__ __launch_bounds__(256) void k1a_xproj(
    const float* __restrict__ x_num, const int* __restrict__ x_cat,
    const char* __restrict__ wsb, unsigned short* __restrict__ xrow,
    float* __restrict__ xstat)
{
  __shared__ float ctile[4][16][100];   // per-wave C-tile, 25600 B
  const int tid = threadIdx.x;
  const int wv = tid >> 6, l = tid & 63, lr = l & 15, lq = l >> 4;
  const int s = blockIdx.x*64 + wv*16 + lr;

  bf16x8 xpf[6];
  {
    const bf16x8* xp = (const bf16x8*)(wsb + O_XPFR);
    #pragma unroll
    for (int nt = 0; nt < 6; ++nt) xpf[nt] = xp[nt*64 + l];
  }
  const float* biast = (const float*)(wsb + O_BIAST);
  const unsigned short* tab2 = (const unsigned short*)(wsb + O_TAB2);
  const f32x4 zero4 = {0.f, 0.f, 0.f, 0.f};

  for (int t = 0; t < 7; ++t) {
    const long ct = (long)s*7 + t;
    // ---- x_num A-frag + MFMA ----
    union { bf16x8 v; unsigned short u[8]; } au;
    {
      const float* xnp = x_num + ct*32 + lq*8;
      float xf[8];
      *(float4*)&xf[0] = *(const float4*)xnp;
      *(float4*)&xf[4] = *(const float4*)(xnp + 4);
      #pragma unroll
      for (int j = 0; j < 8; ++j) au.u[j] = f2b(xf[j]);
    }
    f32x4 xacc[6];
    #pragma unroll
    for (int nt = 0; nt < 6; ++nt)
      xacc[nt] = __builtin_amdgcn_mfma_f32_16x16x32_bf16(au.v, xpf[nt], zero4, 0, 0, 0);
    // ---- scatter C + bias to ctile (rows lq*4+i) ----
    #pragma unroll
    for (int nt = 0; nt < 6; ++nt) {
      float bi = biast[t*96 + nt*16 + lr];
      #pragma unroll
      for (int i = 0; i < 4; ++i)
        ctile[wv][lq*4 + i][nt*16 + lr] = xacc[nt][i] + bi;
    }
    // ---- embedding gather (row lr, cols lq*24..+23) ----
    int idx[16];
    {
      const int4* ip = (const int4*)(x_cat + ct*16);
      int4 i0 = ip[0], i1 = ip[1], i2 = ip[2], i3 = ip[3];
      idx[0]=i0.x; idx[1]=i0.y; idx[2]=i0.z; idx[3]=i0.w;
      idx[4]=i1.x; idx[5]=i1.y; idx[6]=i1.z; idx[7]=i1.w;
      idx[8]=i2.x; idx[9]=i2.y; idx[10]=i2.z; idx[11]=i2.w;
      idx[12]=i3.x; idx[13]=i3.y; idx[14]=i3.z; idx[15]=i3.w;
    }
    float ga[24];
    #pragma unroll
    for (int u = 0; u < 24; ++u) ga[u] = 0.f;
    #pragma unroll
    for (int c = 0; c < 16; ++c) {
      const uint4* tp = (const uint4*)tab2 + (c*101 + idx[c])*12 + lq*3;
      uint4 w0 = tp[0], w1 = tp[1], w2 = tp[2];
      unsigned wb[12] = {w0.x,w0.y,w0.z,w0.w, w1.x,w1.y,w1.z,w1.w, w2.x,w2.y,w2.z,w2.w};
      #pragma unroll
      for (int q = 0; q < 12; ++q) { ga[2*q] += lo16(wb[q]); ga[2*q+1] += hi16(wb[q]); }
    }
    asm volatile("s_waitcnt lgkmcnt(0)" ::: "memory");
    __builtin_amdgcn_sched_barrier(0);
    // ---- combine (row lr slice), round once, store + stats ----
    float cv[24];
    #pragma unroll
    for (int q6 = 0; q6 < 6; ++q6)
      *(float4*)&cv[q6*4] = *(const float4*)&ctile[wv][lr][lq*24 + q6*4];
    unsigned ow[12];
    float sm = 0.f, sq = 0.f;
    #pragma unroll
    for (int u = 0; u < 12; ++u) {
      unsigned short u0 = f2b(cv[2*u]   + ga[2*u]);
      unsigned short u1 = f2b(cv[2*u+1] + ga[2*u+1]);
      ow[u] = (unsigned)u0 | ((unsigned)u1 << 16);
      float f0 = b2f(u0), f1 = b2f(u1);
      sm += f0 + f1; sq = fmaf(f0, f0, fmaf(f1, f1, sq));
    }
    {
      uint4* xo = (uint4*)(xrow + ct*96 + lq*24);
      xo[0] = make_uint4(ow[0], ow[1], ow[2], ow[3]);
      xo[1] = make_uint4(ow[4], ow[5], ow[6], ow[7]);
      xo[2] = make_uint4(ow[8], ow[9], ow[10], ow[11]);
    }
    sm += __shfl_xor(sm, 16, 64); sm += __shfl_xor(sm, 32, 64);
    sq += __shfl_xor(sq, 16, 64); sq += __shfl_xor(sq, 32, 64);
    if (lq == 0) {
      float2 o; o.x = sm; o.y = sq;
      *(float2*)(xstat + ct*2) = o;
    }
  }
}

// =================== K1: 7-step MFMA recurrence (x precomputed) ===================
__global__ __launch_bounds__(512, 2) void k1_scan(
    const float* __restrict__ h0, const float* __restrict__ fc2_b,
    const char* __restrict__ wsb, const unsigned short* __restrict__ xrow,
    const float* __restrict__ xstat, unsigned short* __restrict__ feat,
    float* __restrict__ statg)
{
  extern __shared__ char smem[];
  unsigned short* zg = (unsigned short*)smem;              // [128][200] u16, 51200 B
  unsigned short* f1f = (unsigned short*)(smem + 51200);   // 73728 B
  unsigned short* f2f = (unsigned short*)(smem + 124928);  // 36864 B

  const int tid = threadIdx.x;
  const int wv = tid >> 6;
  const int l = tid & 63;
  const int lr = l & 15;
  const int lq = l >> 4;
  const int rowt = wv*16 + lr;

  { // stage frag tables to LDS
    const uint4* s1 = (const uint4*)(wsb + O_FC1FR);
    uint4* d1 = (uint4*)f1f;
    for (int o = tid; o < 4608; o += 512) d1[o] = s1[o];
    const uint4* s2 = (const uint4*)(wsb + O_FC2FR);
    uint4* d2 = (uint4*)f2f;
    for (int o = tid; o < 2304; o += 512) d2[o] = s2[o];
  }
  const bf16x8* f1v = (const bf16x8*)f1f;
  const bf16x8* f2v = (const bf16x8*)f2f;

  float C1[12], B1[12];
  {
    const float* fc1C = (const float*)(wsb + O_FC1C);
    const float* fc1BP = (const float*)(wsb + O_FC1BP);
    #pragma unroll
    for (int nt = 0; nt < 12; ++nt) { C1[nt] = fc1C[nt*16+lr]; B1[nt] = fc1BP[nt*16+lr]; }
  }
  float fb2[6];
  #pragma unroll
  for (int nt = 0; nt < 6; ++nt) fb2[nt] = fc2_b[nt*16+lr];

  float h[24], hs[24], hm[24];
  #pragma unroll
  for (int nt = 0; nt < 6; ++nt) {
    float v = h0[nt*16+lr];
    #pragma unroll
    for (int i = 0; i < 4; ++i) { h[nt*4+i] = v; hs[nt*4+i] = 0.f; hm[nt*4+i] = -3.4e38f; }
  }
  __syncthreads();

  const f32x4 zero4 = {0.f, 0.f, 0.f, 0.f};
  const size_t srow_q = (size_t)blockIdx.x*128 + wv*16;    // wave sample base

  for (int t = 0; t < 7; ++t) {
    // ---- (a) write h (bf16) to zg cols 0..95 + C-layout row stats ----
    float hsm[4] = {0.f,0.f,0.f,0.f}, hsq[4] = {0.f,0.f,0.f,0.f};
    #pragma unroll
    for (int nt = 0; nt < 6; ++nt) {
      #pragma unroll
      for (int i = 0; i < 4; ++i) {
        unsigned short hb = f2b(h[nt*4+i]);
        zg[(wv*16 + lq*4 + i)*200 + nt*16 + lr] = hb;
        float hf = b2f(hb);
        hsm[i] += hf; hsq[i] = fmaf(hf, hf, hsq[i]);
      }
    }
    #pragma unroll
    for (int i = 0; i < 4; ++i) {
      hsm[i] += __shfl_xor(hsm[i], 1, 64); hsm[i] += __shfl_xor(hsm[i], 2, 64);
      hsm[i] += __shfl_xor(hsm[i], 4, 64); hsm[i] += __shfl_xor(hsm[i], 8, 64);
      hsq[i] += __shfl_xor(hsq[i], 1, 64); hsq[i] += __shfl_xor(hsq[i], 2, 64);
      hsq[i] += __shfl_xor(hsq[i], 4, 64); hsq[i] += __shfl_xor(hsq[i], 8, 64);
    }
    // ---- (b) combine with precomputed x-stats ----
    float mr[4], rr[4];
    #pragma unroll
    for (int i = 0; i < 4; ++i) {
      const float2 xs = *(const float2*)(xstat + ((srow_q + lq*4 + i)*7 + t)*2);
      float m = (hsm[i] + xs.x) * (1.f/192.f);
      float var = (hsq[i] + xs.y) * (1.f/192.f) - m*m;
      mr[i] = m; rr[i] = rsqrtf(var + 1e-5f);
    }
    // ---- (c) fc1 GEMM: A = [h from LDS | x from global] ----
    bf16x8 ax[3];
    {
      const unsigned short* xp = xrow + ((srow_q + lr)*7 + t)*96;
      #pragma unroll
      for (int k3 = 0; k3 < 3; ++k3)
        ax[k3] = *(const bf16x8*)(xp + k3*32 + lq*8);
    }
    f32x4 acc[12];
    #pragma unroll
    for (int nt = 0; nt < 12; ++nt) acc[nt] = zero4;
    #pragma unroll
    for (int ks = 0; ks < 3; ++ks) {
      bf16x8 a = *(const bf16x8*)(zg + rowt*200 + ks*32 + lq*8);
      #pragma unroll
      for (int nt = 0; nt < 12; ++nt)
        acc[nt] = __builtin_amdgcn_mfma_f32_16x16x32_bf16(a, f1v[(nt*6+ks)*64 + l], acc[nt], 0, 0, 0);
    }
    #pragma unroll
    for (int k3 = 0; k3 < 3; ++k3) {
      #pragma unroll
      for (int nt = 0; nt < 12; ++nt)
        acc[nt] = __builtin_amdgcn_mfma_f32_16x16x32_bf16(ax[k3], f1v[(nt*6+k3+3)*64 + l], acc[nt], 0, 0, 0);
    }
    // ---- (d) LN-finish + gelu -> g (cols 0..191) ----
    #pragma unroll
    for (int nt = 0; nt < 12; ++nt) {
      #pragma unroll
      for (int i = 0; i < 4; ++i) {
        float hid = rr[i]*(acc[nt][i] - mr[i]*C1[nt]) + B1[nt];
        zg[(wv*16 + lq*4 + i)*200 + nt*16 + lr] = f2b(geluf(hid));
      }
    }
    // ---- (e) fc2 GEMM ----
    f32x4 a2[6];
    #pragma unroll
    for (int nt = 0; nt < 6; ++nt) a2[nt] = zero4;
    #pragma unroll
    for (int ks = 0; ks < 6; ++ks) {
      bf16x8 a = *(const bf16x8*)(zg + rowt*200 + ks*32 + lq*8);
      #pragma unroll
      for (int nt = 0; nt < 6; ++nt)
        a2[nt] = __builtin_amdgcn_mfma_f32_16x16x32_bf16(a, f2v[(nt*6+ks)*64 + l], a2[nt], 0, 0, 0);
    }
    // ---- (f) h update ----
    #pragma unroll
    for (int nt = 0; nt < 6; ++nt) {
      #pragma unroll
      for (int i = 0; i < 4; ++i) {
        int u = nt*4 + i;
        h[u] += a2[nt][i] + fb2[nt];
        hs[u] += h[u];
        hm[u] = fmaxf(hm[u], h[u]);
      }
    }
  }
  // ---- feat out + partial z-stats ----
  float st[4] = {0.f,0.f,0.f,0.f}, qt[4] = {0.f,0.f,0.f,0.f};
  #pragma unroll
  for (int nt = 0; nt < 6; ++nt) {
    #pragma unroll
    for (int i = 0; i < 4; ++i) {
      size_t r = (srow_q + lq*4 + i)*288;
      int c = nt*16 + lr;
      unsigned short b0 = f2b(h[nt*4+i]);
      unsigned short b1 = f2b(hs[nt*4+i]*(1.f/7.f));
      unsigned short b2v = f2b(hm[nt*4+i]);
      feat[r + c] = b0;
      feat[r + 96 + c] = b1;
      feat[r + 192 + c] = b2v;
      float f0 = b2f(b0), f1 = b2f(b1), f2v = b2f(b2v);
      st[i] += f0 + f1 + f2v;
      qt[i] = fmaf(f0, f0, fmaf(f1, f1, fmaf(f2v, f2v, qt[i])));
    }
  }
  #pragma unroll
  for (int i = 0; i < 4; ++i) {
    st[i] += __shfl_xor(st[i], 1, 64); st[i] += __shfl_xor(st[i], 2, 64);
    st[i] += __shfl_xor(st[i], 4, 64); st[i] += __shfl_xor(st[i], 8, 64);
    qt[i] += __shfl_xor(qt[i], 1, 64); qt[i] += __shfl_xor(qt[i], 2, 64);
    qt[i] += __shfl_xor(qt[i], 4, 64); qt[i] += __shfl_xor(qt[i], 8, 64);
  }
  if (lr == 0) {
    #pragma unroll
    for (int i = 0; i < 4; ++i) {
      size_t r = srow_q + lq*4 + i;
      float2 o; o.x = st[i]; o.y = qt[i];
      *(float2*)(statg + r*2) = o;
    }
  }
}

// =================== K1b: static MLP via MFMA -> s64/stats/base ===================
__global__ __launch_bounds__(512, 2) void k1b_static(
    const float* __restrict__ x_static, const float* __restrict__ sp2_b,
    const float* __restrict__ base_w, const float* __restrict__ base_b,
    char* __restrict__ wsb)
{
  __shared__ char smem[68608];
  unsigned short* sp1f = (unsigned short*)smem;            // 16384
  unsigned short* sp2f = (unsigned short*)(smem + 16384);  // 16384
  unsigned short* hid  = (unsigned short*)(smem + 32768);  // 34816

  const int tid = threadIdx.x;
  const int wv = tid >> 6, l = tid & 63, lr = l & 15, lq = l >> 4;
  const int srow = blockIdx.x*128 + wv*16;

  { // stage frag tables
    const uint4* s1 = (const uint4*)(wsb + O_SP1FR);
    uint4* d1 = (uint4*)sp1f;
    for (int o = tid; o < 1024; o += 512) d1[o] = s1[o];
    const uint4* s2 = (const uint4*)(wsb + O_SP2FR);
    uint4* d2 = (uint4*)sp2f;
    for (int o = tid; o < 1024; o += 512) d2[o] = s2[o];
  }
  __syncthreads();

  float x0f[8], x1f[8];
  {
    const float* xr = x_static + (size_t)(srow + lr)*64;
    *(float4*)&x0f[0] = *(const float4*)(xr + lq*8);
    *(float4*)&x0f[4] = *(const float4*)(xr + lq*8 + 4);
    *(float4*)&x1f[0] = *(const float4*)(xr + 32 + lq*8);
    *(float4*)&x1f[4] = *(const float4*)(xr + 32 + lq*8 + 4);
  }
  float sm = 0.f, sq = 0.f, bp = 0.f;
  #pragma unroll
  for (int j = 0; j < 8; ++j) {
    sm += x0f[j] + x1f[j];
    sq = fmaf(x0f[j], x0f[j], fmaf(x1f[j], x1f[j], sq));
    bp = fmaf(x0f[j], base_w[lq*8 + j], fmaf(x1f[j], base_w[32 + lq*8 + j], bp));
  }
  sm += __shfl_xor(sm, 16, 64); sm += __shfl_xor(sm, 32, 64);
  sq += __shfl_xor(sq, 16, 64); sq += __shfl_xor(sq, 32, 64);
  bp += __shfl_xor(bp, 16, 64); bp += __shfl_xor(bp, 32, 64);
  if (lq == 0) ((float*)(wsb + O_BASE))[srow + lr] = bp + base_b[0];
  const float ms = sm*(1.f/64.f);
  const float rs = rsqrtf(sq*(1.f/64.f) - ms*ms + 1e-5f);
  float mr[4], rr[4];
  #pragma unroll
  for (int i = 0; i < 4; ++i) {
    mr[i] = __shfl(ms, lq*4 + i, 16);
    rr[i] = __shfl(rs, lq*4 + i, 16);
  }
  union { bf16x8 v; unsigned short u[8]; } ua0, ua1;
  #pragma unroll
  for (int j = 0; j < 8; ++j) { ua0.u[j] = f2b(x0f[j]); ua1.u[j] = f2b(x1f[j]); }

  const f32x4 zero4 = {0.f, 0.f, 0.f, 0.f};
  const bf16x8* f1 = (const bf16x8*)sp1f;
  const bf16x8* f2 = (const bf16x8*)sp2f;
  unsigned short* hw = hid + wv*2176;

  f32x4 acc[8];
  #pragma unroll
  for (int nt = 0; nt < 8; ++nt) acc[nt] = zero4;
  #pragma unroll
  for (int nt = 0; nt < 8; ++nt) {
    acc[nt] = __builtin_amdgcn_mfma_f32_16x16x32_bf16(ua0.v, f1[(nt*2 + 0)*64 + l], acc[nt], 0, 0, 0);
    acc[nt] = __builtin_amdgcn_mfma_f32_16x16x32_bf16(ua1.v, f1[(nt*2 + 1)*64 + l], acc[nt], 0, 0, 0);
  }
  {
    const float* spC = (const float*)(wsb + O_SPC);
    const float* spB = (const float*)(wsb + O_SPB);
    #pragma unroll
    for (int nt = 0; nt < 8; ++nt) {
      float Cv = spC[nt*16 + lr], Bv = spB[nt*16 + lr];
      #pragma unroll
      for (int i = 0; i < 4; ++i) {
        float hv = rr[i]*(acc[nt][i] - mr[i]*Cv) + Bv;
        hw[(lq*4 + i)*136 + nt*16 + lr] = f2b(geluf(hv));
      }
    }
  }
  f32x4 a2[4];
  #pragma unroll
  for (int nt = 0; nt < 4; ++nt) a2[nt] = zero4;
  #pragma unroll
  for (int ks = 0; ks < 4; ++ks) {
    bf16x8 a = *(const bf16x8*)(hw + lr*136 + ks*32 + lq*8);
    #pragma unroll
    for (int nt = 0; nt < 4; ++nt)
      a2[nt] = __builtin_amdgcn_mfma_f32_16x16x32_bf16(a, f2[(nt*4 + ks)*64 + l], a2[nt], 0, 0, 0);
  }
  float ss[4] = {0.f,0.f,0.f,0.f}, qq[4] = {0.f,0.f,0.f,0.f};
  {
    unsigned short* s64p = (unsigned short*)(wsb + O_S64);
    #pragma unroll
    for (int nt = 0; nt < 4; ++nt) {
      float bv = sp2_b[nt*16 + lr];
      #pragma unroll
      for (int i = 0; i < 4; ++i) {
        unsigned short rb = f2b(a2[nt][i] + bv);
        s64p[(size_t)(srow + lq*4 + i)*64 + nt*16 + lr] = rb;
        float f = b2f(rb);
        ss[i] += f; qq[i] = fmaf(f, f, qq[i]);
      }
    }
  }
  #pragma unroll
  for (int i = 0; i < 4; ++i) {
    ss[i] += __shfl_xor(ss[i], 1, 64); ss[i] += __shfl_xor(ss[i], 2, 64);
    ss[i] += __shfl_xor(ss[i], 4, 64); ss[i] += __shfl_xor(ss[i], 8, 64);
    qq[i] += __shfl_xor(qq[i], 1, 64); qq[i] += __shfl_xor(qq[i], 2, 64);
    qq[i] += __shfl_xor(qq[i], 4, 64); qq[i] += __shfl_xor(qq[i], 8, 64);
  }
  if (lr == 0) {
    float* stat = (float*)(wsb + O_STAT);
    #pragma unroll
    for (int i = 0; i < 4; ++i) {
      size_t r = (size_t)srow + lq*4 + i;
      float2 fs = *(float2*)(stat + r*2);
      float stot = fs.x + ss[i], qtot = fs.y + qq[i];
      float m = stot*(1.f/352.f);
      float var = qtot*(1.f/352.f) - m*m;
      float2 o; o.x = m; o.y = rsqrtf(var + 1e-5f);
      *(float2*)(stat + r*2) = o;
    }
  }
}

// =================== K2b: heads, weights resident in LDS ===================
__global__ __launch_bounds__(512, 2) void k2b_heads(
    const float* __restrict__ hm2_b, const float* __restrict__ hq2_b,
    const float* __restrict__ hn2_b, const char* __restrict__ wsb,
    const unsigned short* __restrict__ feat, float* __restrict__ out)
{
  extern __shared__ char smem[];
  const int g = blockIdx.y;
  const int tid = threadIdx.x;
  const int wv = tid >> 6, l = tid & 63, lr = l & 15, lq = l >> 4;
  const int ntn = (g == 2) ? 6 : 12;
  {
    const uint4* src = (const uint4*)(wsb + O_HDFR + (size_t)g*135168);
    uint4* dst = (uint4*)smem;
    const int n = ntn*11*64;
    for (int o = tid; o < n; o += 512) dst[o] = src[o];
  }
  __syncthreads();
  const bf16x8* wfr = (const bf16x8*)smem;
  const float* hdC = (const float*)(wsb + O_HDC);
  const float* hdB = (const float*)(wsb + O_HDBP);
  const float* w2c = (const float*)(wsb + O_W2C);
  const float* stat = (const float*)(wsb + O_STAT);
  const float* baseb = (const float*)(wsb + O_BASE);
  const unsigned short* s64p = (const unsigned short*)(wsb + O_S64);
  const float hb = (g == 0) ? hm2_b[0] : (g == 1) ? hq2_b[0] : hn2_b[0];
  const f32x4 zero4 = {0.f, 0.f, 0.f, 0.f};

  for (int c = blockIdx.x; c < 256; c += gridDim.x) {
    const int base = c*256 + wv*32;
    bf16x8 afr0[11], afr1[11];
    {
      const unsigned short* fr0 = feat + (size_t)(base + lr)*288;
      const unsigned short* fr1 = feat + (size_t)(base + 16 + lr)*288;
      #pragma unroll
      for (int ks = 0; ks < 9; ++ks) {
        afr0[ks] = *(const bf16x8*)(fr0 + ks*32 + lq*8);
        afr1[ks] = *(const bf16x8*)(fr1 + ks*32 + lq*8);
      }
      const unsigned short* sr0 = s64p + (size_t)(base + lr)*64;
      const unsigned short* sr1 = s64p + (size_t)(base + 16 + lr)*64;
      afr0[9]  = *(const bf16x8*)(sr0 + lq*8);
      afr0[10] = *(const bf16x8*)(sr0 + 32 + lq*8);
      afr1[9]  = *(const bf16x8*)(sr1 + lq*8);
      afr1[10] = *(const bf16x8*)(sr1 + 32 + lq*8);
    }
    float mr0[4], rr0[4], mr1[4], rr1[4];
    #pragma unroll
    for (int i = 0; i < 4; ++i) {
      float2 s0 = *(const float2*)(stat + (size_t)(base + lq*4 + i)*2);
      float2 s1 = *(const float2*)(stat + (size_t)(base + 16 + lq*4 + i)*2);
      mr0[i] = s0.x; rr0[i] = s0.y; mr1[i] = s1.x; rr1[i] = s1.y;
    }
    float pr0[4] = {0.f,0.f,0.f,0.f}, pr1[4] = {0.f,0.f,0.f,0.f};
    for (int nt = 0; nt < ntn; ++nt) {
      const int col = (g*12 + nt)*16 + lr;
      const float Cv = hdC[col], Bv = hdB[col], w2v = w2c[col];
      f32x4 a0 = zero4, a1v = zero4;
      #pragma unroll
      for (int ks = 0; ks < 11; ++ks) {
        bf16x8 b = wfr[(nt*11 + ks)*64 + l];
        a0  = __builtin_amdgcn_mfma_f32_16x16x32_bf16(afr0[ks], b, a0, 0, 0, 0);
        a1v = __builtin_amdgcn_mfma_f32_16x16x32_bf16(afr1[ks], b, a1v, 0, 0, 0);
      }
      #pragma unroll
      for (int i = 0; i < 4; ++i) {
        pr0[i] += geluf(rr0[i]*(a0[i]  - mr0[i]*Cv) + Bv) * w2v;
        pr1[i] += geluf(rr1[i]*(a1v[i] - mr1[i]*Cv) + Bv) * w2v;
      }
    }
    #pragma unroll
    for (int i = 0; i < 4; ++i) {
      float v0 = pr0[i], v1 = pr1[i];
      v0 += __shfl_xor(v0, 1, 64); v0 += __shfl_xor(v0, 2, 64);
      v0 += __shfl_xor(v0, 4, 64); v0 += __shfl_xor(v0, 8, 64);
      v1 += __shfl_xor(v1, 1, 64); v1 += __shfl_xor(v1, 2, 64);
      v1 += __shfl_xor(v1, 4, 64); v1 += __shfl_xor(v1, 8, 64);
      if (lr == 0) {
        int r0 = base + lq*4 + i;
        int r1 = base + 16 + lq*4 + i;
        float b0 = (g < 2) ? baseb[r0] : 0.f;
        float b1 = (g < 2) ? baseb[r1] : 0.f;
        out[(size_t)g*NB + r0] = b0 + hb + v0;
        out[(size_t)g*NB + r1] = b1 + hb + v1;
      }
    }
  }
}

extern "C" void kernel_launch(void* const* d_in, const int* in_sizes, int n_in,
                              void* d_out, int out_size, void* d_ws, size_t ws_size,
                              hipStream_t stream) {
  (void)in_sizes; (void)n_in; (void)out_size; (void)ws_size;
  const float* x_num    = (const float*)d_in[0];
  const float* x_static = (const float*)d_in[1];
  const int*   x_cat    = (const int*)  d_in[2];
  const float* cat_emb  = (const float*)d_in[3];
  const float* day_emb  = (const float*)d_in[4];
  const float* xproj_w  = (const float*)d_in[5];
  const float* xproj_b  = (const float*)d_in[6];
  const float* h0       = (const float*)d_in[7];
  const float* bln_g    = (const float*)d_in[8];
  const float* bln_b    = (const float*)d_in[9];
  const float* fc1_w    = (const float*)d_in[10];
  const float* fc1_b    = (const float*)d_in[11];
  const float* fc2_w    = (const float*)d_in[12];
  const float* fc2_b    = (const float*)d_in[13];
  const float* spln_g   = (const float*)d_in[14];
  const float* spln_b   = (const float*)d_in[15];
  const float* sp1_w    = (const float*)d_in[16];
  const float* sp1_b    = (const float*)d_in[17];
  const float* sp2_w    = (const float*)d_in[18];
  const float* sp2_b    = (const float*)d_in[19];
  const float* base_w   = (const float*)d_in[20];
  const float* base_b   = (const float*)d_in[21];
  const float* hln_g    = (const float*)d_in[22];
  const float* hln_b    = (const float*)d_in[23];
  const float* hm1_w    = (const float*)d_in[24];
  const float* hm1_b    = (const float*)d_in[25];
  const float* hm2_w    = (const float*)d_in[26];
  const float* hm2_b    = (const float*)d_in[27];
  const float* hq1_w    = (const float*)d_in[28];
  const float* hq1_b    = (const float*)d_in[29];
  const float* hq2_w    = (const float*)d_in[30];
  const float* hq2_b    = (const float*)d_in[31];
  const float* hn1_w    = (const float*)d_in[32];
  const float* hn1_b    = (const float*)d_in[33];
  const float* hn2_w    = (const float*)d_in[34];
  const float* hn2_b    = (const float*)d_in[35];

  char* wsb = (char*)d_ws;
  unsigned short* feat = (unsigned short*)(wsb + O_FEAT);
  unsigned short* xrow = (unsigned short*)(wsb + O_XROW);
  float* xstat = (float*)(wsb + O_XSTAT);
  float* statg = (float*)(wsb + O_STAT);
  float* out = (float*)d_out;

  k0_pre<<<2098, 512, 0, stream>>>(cat_emb, day_emb, xproj_w, xproj_b,
      bln_g, bln_b, fc1_w, fc1_b, fc2_w, spln_g, spln_b, sp1_w, sp1_b, sp2_w,
      hln_g, hln_b, hm1_w, hm1_b, hq1_w, hq1_b, hn1_w, hn1_b,
      hm2_w, hq2_w, hn2_w, wsb);
  k1a_xproj<<<1024, 256, 0, stream>>>(x_num, x_cat, wsb, xrow, xstat);
  k1_scan<<<512, 512, 161792, stream>>>(h0, fc2_b, wsb, xrow, xstat, feat, statg);
  k1b_static<<<512, 512, 0, stream>>>(x_static, sp2_b, base_w, base_b, wsb);
  k2b_heads<<<dim3(86, 3), 512, 135168, stream>>>(hm2_b, hq2_b, hn2_b,
      wsb, feat, out);
}

// Round 6
// 319.405 us; speedup vs baseline: 32.2300x; 1.1954x over previous
//
#include <hip/hip_runtime.h>
#include <math.h>

#define NB 65536

typedef __attribute__((ext_vector_type(8))) short bf16x8;
typedef __attribute__((ext_vector_type(4))) float f32x4;

// ---- ws byte offsets ----
#define O_BIAST  0         // f32 [7][96]                 2688
#define O_FC1C   4096      // f32 [192]
#define O_FC1BP  8192      // f32 [192]
#define O_FC1FR  12288     // u16 [72][64][8]   73728  -> 86016
#define O_FC2FR  86016     // u16 [36][64][8]   36864  -> 122880
#define O_HDFR   122880    // u16 [330][64][8]  337920 -> 460800
#define O_HDC    460800    // f32 [480]
#define O_HDBP   462848    // f32 [480]
#define O_W2C    464896    // f32 [480]
#define O_SPC    466944    // f32 [128]
#define O_SPB    467968    // f32 [128]
#define O_SP1FR  468992    // u16 [16][64][8]   16384  -> 485376
#define O_SP2FR  485376    // u16 [16][64][8]   16384  -> 501760
#define O_XP2FR  501760    // u16 [54][64][8]   55296  -> 557056
#define O_EMB16  557056    // u16 [16][101][16] 51712  -> 608768
#define O_FEAT   608768    // u16 [65536][288]  37748736 -> 38357504
#define O_S64    38357504  // u16 [65536][64]   8388608  -> 46746112
#define O_STAT   46746112  // f32 [65536][2]    524288   -> 47270400
#define O_BASE   47270400  // f32 [65536]       262144   -> 47532544
#define O_XROW   47532544  // u16 [458752][96]  88080384 -> 135612928
#define O_XSTAT  135612928 // f32 [458752][2]   3670016  -> 139282944

__device__ __forceinline__ unsigned short f2b(float x) {
  unsigned int u = __float_as_uint(x);
  u += 0x7fffu + ((u >> 16) & 1u);   // RNE bf16
  return (unsigned short)(u >> 16);
}
__device__ __forceinline__ float b2f(unsigned short u) {
  return __uint_as_float(((unsigned)u) << 16);
}
__device__ __forceinline__ float geluf(float x) {
  return 0.5f * x * (1.0f + erff(x * 0.70710678118654752f));
}

// =================== K0: fold + frag-pack all weights ===================
__global__ void k0_pre(
    const float* __restrict__ cat_emb, const float* __restrict__ day_emb,
    const float* __restrict__ xproj_w, const float* __restrict__ xproj_b,
    const float* __restrict__ bln_g, const float* __restrict__ bln_b,
    const float* __restrict__ fc1_w, const float* __restrict__ fc1_b,
    const float* __restrict__ fc2_w,
    const float* __restrict__ spln_g, const float* __restrict__ spln_b,
    const float* __restrict__ sp1_w, const float* __restrict__ sp1_b,
    const float* __restrict__ sp2_w,
    const float* __restrict__ hln_g, const float* __restrict__ hln_b,
    const float* __restrict__ hm1_w, const float* __restrict__ hm1_b,
    const float* __restrict__ hq1_w, const float* __restrict__ hq1_b,
    const float* __restrict__ hn1_w, const float* __restrict__ hn1_b,
    const float* __restrict__ hm2_w, const float* __restrict__ hq2_w,
    const float* __restrict__ hn2_w,
    char* __restrict__ wsb)
{
  const int b = blockIdx.x, tid = threadIdx.x;
  if (b < 7) {                        // per-t bias (xproj_b + day part)
    if (tid < 96) {
      int t = b;
      float acc = xproj_b[tid];
      #pragma unroll
      for (int d = 0; d < 8; ++d)
        acc = fmaf(day_emb[(1+t)*8 + d], xproj_w[(288+d)*96 + tid], acc);
      ((float*)(wsb + O_BIAST))[t*96 + tid] = acc;
    }
  } else if (b < 9) {                 // fc1 LN-fold C / B'
    if (tid < 96) {
      int col = (b-7)*96 + tid;
      float C = 0.f, Bp = fc1_b[col];
      for (int k = 0; k < 192; ++k) {
        float w = fc1_w[k*192 + col];
        C = fmaf(bln_g[k], w, C);
        Bp = fmaf(bln_b[k], w, Bp);
      }
      ((float*)(wsb + O_FC1C))[col] = C;
      ((float*)(wsb + O_FC1BP))[col] = Bp;
    }
  } else if (b < 81) {                // fc1 frags [nt(12)][ks(6)]
    int seg = b - 9, nt = seg / 6, ks = seg - nt*6;
    int ln = tid >> 3, j = tid & 7;
    int k = ks*32 + (ln>>4)*8 + j, col = nt*16 + (ln&15);
    ((unsigned short*)(wsb + O_FC1FR))[(seg*64 + ln)*8 + j] = f2b(bln_g[k]*fc1_w[k*192 + col]);
  } else if (b < 117) {               // fc2 frags [nt(6)][ks(6)]
    int seg = b - 81, nt = seg / 6, ks = seg - nt*6;
    int ln = tid >> 3, j = tid & 7;
    int k = ks*32 + (ln>>4)*8 + j, col = nt*16 + (ln&15);
    ((unsigned short*)(wsb + O_FC2FR))[(seg*64 + ln)*8 + j] = f2b(fc2_w[k*96 + col]);
  } else if (b < 447) {               // head frags [nt(30)][ks(11)]
    int seg = b - 117, nt = seg / 11, ks = seg - nt*11;
    int ln = tid >> 3, j = tid & 7;
    int k = ks*32 + (ln>>4)*8 + j, gcol = nt*16 + (ln&15);
    float w;
    if (gcol < 192) w = hm1_w[k*192 + gcol];
    else if (gcol < 384) w = hq1_w[k*192 + (gcol-192)];
    else w = hn1_w[k*96 + (gcol-384)];
    ((unsigned short*)(wsb + O_HDFR))[(seg*64 + ln)*8 + j] = f2b(hln_g[k]*w);
  } else if (b < 448) {               // head C / B' / w2 concat
    if (tid < 480) {
      int gcol = tid;
      float C = 0.f, Bp, w2;
      if (gcol < 192) { Bp = hm1_b[gcol]; w2 = hm2_w[gcol]; }
      else if (gcol < 384) { Bp = hq1_b[gcol-192]; w2 = hq2_w[gcol-192]; }
      else { Bp = hn1_b[gcol-384]; w2 = hn2_w[gcol-384]; }
      for (int k = 0; k < 352; ++k) {
        float w;
        if (gcol < 192) w = hm1_w[k*192 + gcol];
        else if (gcol < 384) w = hq1_w[k*192 + (gcol-192)];
        else w = hn1_w[k*96 + (gcol-384)];
        C = fmaf(hln_g[k], w, C);
        Bp = fmaf(hln_b[k], w, Bp);
      }
      ((float*)(wsb + O_HDC))[gcol] = C;
      ((float*)(wsb + O_HDBP))[gcol] = Bp;
      ((float*)(wsb + O_W2C))[gcol] = w2;
    }
  } else if (b < 449) {               // sp1 LN-fold (C from bf16-rounded weights)
    if (tid < 128) {
      int col = tid;
      float C = 0.f, Bp = sp1_b[col];
      for (int k = 0; k < 64; ++k) {
        float w = sp1_w[k*128 + col];
        C += b2f(f2b(spln_g[k]*w));
        Bp = fmaf(spln_b[k], w, Bp);
      }
      ((float*)(wsb + O_SPC))[col] = C;
      ((float*)(wsb + O_SPB))[col] = Bp;
    }
  } else if (b < 465) {               // sp1 frags [nt(8)][ks(2)]
    int seg = b - 449;
    int ln = tid >> 3, j = tid & 7;
    int nt = seg >> 1, ks = seg & 1;
    int k = ks*32 + (ln>>4)*8 + j, col = nt*16 + (ln&15);
    ((unsigned short*)(wsb + O_SP1FR))[(seg*64 + ln)*8 + j] = f2b(spln_g[k]*sp1_w[k*128 + col]);
  } else if (b < 481) {               // sp2 frags [nt(4)][ks(4)]
    int seg = b - 465;
    int ln = tid >> 3, j = tid & 7;
    int ks = seg & 3;
    int k = ks*32 + (ln>>4)*8 + j, col = (seg >> 2)*16 + (ln&15);
    ((unsigned short*)(wsb + O_SP2FR))[(seg*64 + ln)*8 + j] = f2b(sp2_w[k*64 + col]);
  } else if (b < 535) {               // xproj K=288 frags [ks(9)][nt(6)]
    int seg = b - 481, ks = seg / 6, nt = seg - ks*6;
    int ln = tid >> 3, j = tid & 7;
    int k = ks*32 + (ln>>4)*8 + j, col = nt*16 + (ln&15);
    ((unsigned short*)(wsb + O_XP2FR))[(seg*64 + ln)*8 + j] = f2b(xproj_w[k*96 + col]);
  } else {                            // raw emb table -> bf16 [16][101][16]
    int i = (b - 535)*512 + tid;
    if (i < 25856)
      ((unsigned short*)(wsb + O_EMB16))[i] = f2b(cat_emb[i]);
  }
}

// =================== K1a: x-projection, K=288 MFMA with raw-emb A-frags ===================
// 256 thr = 4 waves; 64 (s,t) rows per block; 1 row/thread-slot, no t loop.
__global__ __launch_bounds__(256) void k1a_xproj(
    const float* __restrict__ x_num, const int* __restrict__ x_cat,
    const char* __restrict__ wsb, unsigned short* __restrict__ xrow,
    float* __restrict__ xstat)
{
  __shared__ float ctile[4][16][100];   // 25600 B (stride 400B: 16B-aligned, 2-way banks)
  __shared__ float bsh[7][96];          // 2688 B
  const int tid = threadIdx.x;
  const int wv = tid >> 6, l = tid & 63, lr = l & 15, lq = l >> 4;
  const unsigned ct = blockIdx.x*64u + wv*16u + lr;   // flat (s,t) row
  const int lqh = lq >> 1, lql = lq & 1;

  if (tid < 168)
    ((float4*)bsh)[tid] = ((const float4*)(wsb + O_BIAST))[tid];
  __syncthreads();

  // ---- x_cat indices: this lane needs cats {2k+lqh}, k=0..7 ----
  int e0,e1,e2,e3,e4,e5,e6,e7;
  {
    const int4* ip = (const int4*)(x_cat + (size_t)ct*16);
    int4 v0 = ip[0], v1 = ip[1], v2 = ip[2], v3 = ip[3];
    e0 = lqh ? v0.y : v0.x;  e1 = lqh ? v0.w : v0.z;
    e2 = lqh ? v1.y : v1.x;  e3 = lqh ? v1.w : v1.z;
    e4 = lqh ? v2.y : v2.x;  e5 = lqh ? v2.w : v2.z;
    e6 = lqh ? v3.y : v3.x;  e7 = lqh ? v3.w : v3.z;
  }
  // ---- A-frags: af[0] = x_num (cvt), af[1..8] = raw emb bf16 (direct 16B loads) ----
  const unsigned short* emb = (const unsigned short*)(wsb + O_EMB16);
  bf16x8 af[9];
  {
    const float* xnp = x_num + (size_t)ct*32 + lq*8;
    float xf[8];
    *(float4*)&xf[0] = *(const float4*)xnp;
    *(float4*)&xf[4] = *(const float4*)(xnp + 4);
    union { bf16x8 v; unsigned short u[8]; } au;
    #pragma unroll
    for (int j = 0; j < 8; ++j) au.u[j] = f2b(xf[j]);
    af[0] = au.v;
  }
  af[1] = *(const bf16x8*)(emb + ((0*2+lqh)*101 + e0)*16 + lql*8);
  af[2] = *(const bf16x8*)(emb + ((1*2+lqh)*101 + e1)*16 + lql*8);
  af[3] = *(const bf16x8*)(emb + ((2*2+lqh)*101 + e2)*16 + lql*8);
  af[4] = *(const bf16x8*)(emb + ((3*2+lqh)*101 + e3)*16 + lql*8);
  af[5] = *(const bf16x8*)(emb + ((4*2+lqh)*101 + e4)*16 + lql*8);
  af[6] = *(const bf16x8*)(emb + ((5*2+lqh)*101 + e5)*16 + lql*8);
  af[7] = *(const bf16x8*)(emb + ((6*2+lqh)*101 + e6)*16 + lql*8);
  af[8] = *(const bf16x8*)(emb + ((7*2+lqh)*101 + e7)*16 + lql*8);

  // ---- K=288 GEMM: acc[nt] over 9 k-steps (B streamed from L1/L2) ----
  const bf16x8* xp2 = (const bf16x8*)(wsb + O_XP2FR);
  const f32x4 zero4 = {0.f, 0.f, 0.f, 0.f};
  f32x4 acc[6];
  #pragma unroll
  for (int nt = 0; nt < 6; ++nt) acc[nt] = zero4;
  #pragma unroll
  for (int ks = 0; ks < 9; ++ks) {
    #pragma unroll
    for (int nt = 0; nt < 6; ++nt)
      acc[nt] = __builtin_amdgcn_mfma_f32_16x16x32_bf16(af[ks], xp2[(ks*6+nt)*64 + l], acc[nt], 0, 0, 0);
  }
  // ---- scatter C-layout -> ctile ----
  #pragma unroll
  for (int nt = 0; nt < 6; ++nt) {
    #pragma unroll
    for (int i = 0; i < 4; ++i)
      ctile[wv][lq*4 + i][nt*16 + lr] = acc[nt][i];
  }
  asm volatile("s_waitcnt lgkmcnt(0)" ::: "memory");
  __builtin_amdgcn_sched_barrier(0);
  // ---- combine row lr: + bias[t], round once, store + stats ----
  const unsigned t = ct % 7u;
  float cv[24], bv[24];
  #pragma unroll
  for (int q = 0; q < 6; ++q) {
    *(float4*)&cv[q*4] = *(const float4*)&ctile[wv][lr][lq*24 + q*4];
    *(float4*)&bv[q*4] = *(const float4*)&bsh[t][lq*24 + q*4];
  }
  unsigned ow[12];
  float sm = 0.f, sq = 0.f;
  #pragma unroll
  for (int u = 0; u < 12; ++u) {
    unsigned short u0 = f2b(cv[2*u]   + bv[2*u]);
    unsigned short u1 = f2b(cv[2*u+1] + bv[2*u+1]);
    ow[u] = (unsigned)u0 | ((unsigned)u1 << 16);
    float f0 = b2f(u0), f1 = b2f(u1);
    sm += f0 + f1; sq = fmaf(f0, f0, fmaf(f1, f1, sq));
  }
  {
    uint4* xo = (uint4*)(xrow + (size_t)ct*96 + lq*24);
    xo[0] = make_uint4(ow[0], ow[1], ow[2], ow[3]);
    xo[1] = make_uint4(ow[4], ow[5], ow[6], ow[7]);
    xo[2] = make_uint4(ow[8], ow[9], ow[10], ow[11]);
  }
  sm += __shfl_xor(sm, 16, 64); sm += __shfl_xor(sm, 32, 64);
  sq += __shfl_xor(sq, 16, 64); sq += __shfl_xor(sq, 32, 64);
  if (lq == 0) {
    float2 o; o.x = sm; o.y = sq;
    *(float2*)(xstat + (size_t)ct*2) = o;
  }
}

// =================== K1: 7-step MFMA recurrence (x precomputed) ===================
__global__ __launch_bounds__(512, 2) void k1_scan(
    const float* __restrict__ h0, const float* __restrict__ fc2_b,
    const char* __restrict__ wsb, const unsigned short* __restrict__ xrow,
    const float* __restrict__ xstat, unsigned short* __restrict__ feat,
    float* __restrict__ statg)
{
  extern __shared__ char smem[];
  unsigned short* zg = (unsigned short*)smem;              // [128][200] u16, 51200 B
  unsigned short* f1f = (unsigned short*)(smem + 51200);   // 73728 B
  unsigned short* f2f = (unsigned short*)(smem + 124928);  // 36864 B

  const int tid = threadIdx.x;
  const int wv = tid >> 6;
  const int l = tid & 63;
  const int lr = l & 15;
  const int lq = l >> 4;
  const int rowt = wv*16 + lr;

  { // stage frag tables to LDS
    const uint4* s1 = (const uint4*)(wsb + O_FC1FR);
    uint4* d1 = (uint4*)f1f;
    for (int o = tid; o < 4608; o += 512) d1[o] = s1[o];
    const uint4* s2 = (const uint4*)(wsb + O_FC2FR);
    uint4* d2 = (uint4*)f2f;
    for (int o = tid; o < 2304; o += 512) d2[o] = s2[o];
  }
  const bf16x8* f1v = (const bf16x8*)f1f;
  const bf16x8* f2v = (const bf16x8*)f2f;

  float C1[12], B1[12];
  {
    const float* fc1C = (const float*)(wsb + O_FC1C);
    const float* fc1BP = (const float*)(wsb + O_FC1BP);
    #pragma unroll
    for (int nt = 0; nt < 12; ++nt) { C1[nt] = fc1C[nt*16+lr]; B1[nt] = fc1BP[nt*16+lr]; }
  }
  float fb2[6];
  #pragma unroll
  for (int nt = 0; nt < 6; ++nt) fb2[nt] = fc2_b[nt*16+lr];

  float h[24], hs[24], hm[24];
  #pragma unroll
  for (int nt = 0; nt < 6; ++nt) {
    float v = h0[nt*16+lr];
    #pragma unroll
    for (int i = 0; i < 4; ++i) { h[nt*4+i] = v; hs[nt*4+i] = 0.f; hm[nt*4+i] = -3.4e38f; }
  }
  __syncthreads();

  const f32x4 zero4 = {0.f, 0.f, 0.f, 0.f};
  const size_t srow_q = (size_t)blockIdx.x*128 + wv*16;    // wave sample base

  for (int t = 0; t < 7; ++t) {
    // ---- (a) write h (bf16) to zg cols 0..95 + C-layout row stats ----
    float hsm[4] = {0.f,0.f,0.f,0.f}, hsq[4] = {0.f,0.f,0.f,0.f};
    #pragma unroll
    for (int nt = 0; nt < 6; ++nt) {
      #pragma unroll
      for (int i = 0; i < 4; ++i) {
        unsigned short hb = f2b(h[nt*4+i]);
        zg[(wv*16 + lq*4 + i)*200 + nt*16 + lr] = hb;
        float hf = b2f(hb);
        hsm[i] += hf; hsq[i] = fmaf(hf, hf, hsq[i]);
      }
    }
    #pragma unroll
    for (int i = 0; i < 4; ++i) {
      hsm[i] += __shfl_xor(hsm[i], 1, 64); hsm[i] += __shfl_xor(hsm[i], 2, 64);
      hsm[i] += __shfl_xor(hsm[i], 4, 64); hsm[i] += __shfl_xor(hsm[i], 8, 64);
      hsq[i] += __shfl_xor(hsq[i], 1, 64); hsq[i] += __shfl_xor(hsq[i], 2, 64);
      hsq[i] += __shfl_xor(hsq[i], 4, 64); hsq[i] += __shfl_xor(hsq[i], 8, 64);
    }
    // ---- (b) combine with precomputed x-stats ----
    float mr[4], rr[4];
    #pragma unroll
    for (int i = 0; i < 4; ++i) {
      const float2 xs = *(const float2*)(xstat + ((srow_q + lq*4 + i)*7 + t)*2);
      float m = (hsm[i] + xs.x) * (1.f/192.f);
      float var = (hsq[i] + xs.y) * (1.f/192.f) - m*m;
      mr[i] = m; rr[i] = rsqrtf(var + 1e-5f);
    }
    // ---- (c) fc1 GEMM: A = [h from LDS | x from global] ----
    bf16x8 ax[3];
    {
      const unsigned short* xp = xrow + ((srow_q + lr)*7 + t)*96;
      #pragma unroll
      for (int k3 = 0; k3 < 3; ++k3)
        ax[k3] = *(const bf16x8*)(xp + k3*32 + lq*8);
    }
    f32x4 acc[12];
    #pragma unroll
    for (int nt = 0; nt < 12; ++nt) acc[nt] = zero4;
    #pragma unroll
    for (int ks = 0; ks < 3; ++ks) {
      bf16x8 a = *(const bf16x8*)(zg + rowt*200 + ks*32 + lq*8);
      #pragma unroll
      for (int nt = 0; nt < 12; ++nt)
        acc[nt] = __builtin_amdgcn_mfma_f32_16x16x32_bf16(a, f1v[(nt*6+ks)*64 + l], acc[nt], 0, 0, 0);
    }
    #pragma unroll
    for (int k3 = 0; k3 < 3; ++k3) {
      #pragma unroll
      for (int nt = 0; nt < 12; ++nt)
        acc[nt] = __builtin_amdgcn_mfma_f32_16x16x32_bf16(ax[k3], f1v[(nt*6+k3+3)*64 + l], acc[nt], 0, 0, 0);
    }
    // ---- (d) LN-finish + gelu -> g (cols 0..191) ----
    #pragma unroll
    for (int nt = 0; nt < 12; ++nt) {
      #pragma unroll
      for (int i = 0; i < 4; ++i) {
        float hid = rr[i]*(acc[nt][i] - mr[i]*C1[nt]) + B1[nt];
        zg[(wv*16 + lq*4 + i)*200 + nt*16 + lr] = f2b(geluf(hid));
      }
    }
    // ---- (e) fc2 GEMM ----
    f32x4 a2[6];
    #pragma unroll
    for (int nt = 0; nt < 6; ++nt) a2[nt] = zero4;
    #pragma unroll
    for (int ks = 0; ks < 6; ++ks) {
      bf16x8 a = *(const bf16x8*)(zg + rowt*200 + ks*32 + lq*8);
      #pragma unroll
      for (int nt = 0; nt < 6; ++nt)
        a2[nt] = __builtin_amdgcn_mfma_f32_16x16x32_bf16(a, f2v[(nt*6+ks)*64 + l], a2[nt], 0, 0, 0);
    }
    // ---- (f) h update ----
    #pragma unroll
    for (int nt = 0; nt < 6; ++nt) {
      #pragma unroll
      for (int i = 0; i < 4; ++i) {
        int u = nt*4 + i;
        h[u] += a2[nt][i] + fb2[nt];
        hs[u] += h[u];
        hm[u] = fmaxf(hm[u], h[u]);
      }
    }
  }
  // ---- feat out + partial z-stats ----
  float st[4] = {0.f,0.f,0.f,0.f}, qt[4] = {0.f,0.f,0.f,0.f};
  #pragma unroll
  for (int nt = 0; nt < 6; ++nt) {
    #pragma unroll
    for (int i = 0; i < 4; ++i) {
      size_t r = (srow_q + lq*4 + i)*288;
      int c = nt*16 + lr;
      unsigned short b0 = f2b(h[nt*4+i]);
      unsigned short b1 = f2b(hs[nt*4+i]*(1.f/7.f));
      unsigned short b2v = f2b(hm[nt*4+i]);
      feat[r + c] = b0;
      feat[r + 96 + c] = b1;
      feat[r + 192 + c] = b2v;
      float f0 = b2f(b0), f1 = b2f(b1), f2v = b2f(b2v);
      st[i] += f0 + f1 + f2v;
      qt[i] = fmaf(f0, f0, fmaf(f1, f1, fmaf(f2v, f2v, qt[i])));
    }
  }
  #pragma unroll
  for (int i = 0; i < 4; ++i) {
    st[i] += __shfl_xor(st[i], 1, 64); st[i] += __shfl_xor(st[i], 2, 64);
    st[i] += __shfl_xor(st[i], 4, 64); st[i] += __shfl_xor(st[i], 8, 64);
    qt[i] += __shfl_xor(qt[i], 1, 64); qt[i] += __shfl_xor(qt[i], 2, 64);
    qt[i] += __shfl_xor(qt[i], 4, 64); qt[i] += __shfl_xor(qt[i], 8, 64);
  }
  if (lr == 0) {
    #pragma unroll
    for (int i = 0; i < 4; ++i) {
      size_t r = srow_q + lq*4 + i;
      float2 o; o.x = st[i]; o.y = qt[i];
      *(float2*)(statg + r*2) = o;
    }
  }
}

// =================== K1b: static MLP via MFMA -> s64/stats/base ===================
__global__ __launch_bounds__(512, 2) void k1b_static(
    const float* __restrict__ x_static, const float* __restrict__ sp2_b,
    const float* __restrict__ base_w, const float* __restrict__ base_b,
    char* __restrict__ wsb)
{
  __shared__ char smem[68608];
  unsigned short* sp1f = (unsigned short*)smem;            // 16384
  unsigned short* sp2f = (unsigned short*)(smem + 16384);  // 16384
  unsigned short* hid  = (unsigned short*)(smem + 32768);  // 34816

  const int tid = threadIdx.x;
  const int wv = tid >> 6, l = tid & 63, lr = l & 15, lq = l >> 4;
  const int srow = blockIdx.x*128 + wv*16;

  { // stage frag tables
    const uint4* s1 = (const uint4*)(wsb + O_SP1FR);
    uint4* d1 = (uint4*)sp1f;
    for (int o = tid; o < 1024; o += 512) d1[o] = s1[o];
    const uint4* s2 = (const uint4*)(wsb + O_SP2FR);
    uint4* d2 = (uint4*)sp2f;
    for (int o = tid; o < 1024; o += 512) d2[o] = s2[o];
  }
  __syncthreads();

  float x0f[8], x1f[8];
  {
    const float* xr = x_static + (size_t)(srow + lr)*64;
    *(float4*)&x0f[0] = *(const float4*)(xr + lq*8);
    *(float4*)&x0f[4] = *(const float4*)(xr + lq*8 + 4);
    *(float4*)&x1f[0] = *(const float4*)(xr + 32 + lq*8);
    *(float4*)&x1f[4] = *(const float4*)(xr + 32 + lq*8 + 4);
  }
  float sm = 0.f, sq = 0.f, bp = 0.f;
  #pragma unroll
  for (int j = 0; j < 8; ++j) {
    sm += x0f[j] + x1f[j];
    sq = fmaf(x0f[j], x0f[j], fmaf(x1f[j], x1f[j], sq));
    bp = fmaf(x0f[j], base_w[lq*8 + j], fmaf(x1f[j], base_w[32 + lq*8 + j], bp));
  }
  sm += __shfl_xor(sm, 16, 64); sm += __shfl_xor(sm, 32, 64);
  sq += __shfl_xor(sq, 16, 64); sq += __shfl_xor(sq, 32, 64);
  bp += __shfl_xor(bp, 16, 64); bp += __shfl_xor(bp, 32, 64);
  if (lq == 0) ((float*)(wsb + O_BASE))[srow + lr] = bp + base_b[0];
  const float ms = sm*(1.f/64.f);
  const float rs = rsqrtf(sq*(1.f/64.f) - ms*ms + 1e-5f);
  float mr[4], rr[4];
  #pragma unroll
  for (int i = 0; i < 4; ++i) {
    mr[i] = __shfl(ms, lq*4 + i, 16);
    rr[i] = __shfl(rs, lq*4 + i, 16);
  }
  union { bf16x8 v; unsigned short u[8]; } ua0, ua1;
  #pragma unroll
  for (int j = 0; j < 8; ++j) { ua0.u[j] = f2b(x0f[j]); ua1.u[j] = f2b(x1f[j]); }

  const f32x4 zero4 = {0.f, 0.f, 0.f, 0.f};
  const bf16x8* f1 = (const bf16x8*)sp1f;
  const bf16x8* f2 = (const bf16x8*)sp2f;
  unsigned short* hw = hid + wv*2176;

  f32x4 acc[8];
  #pragma unroll
  for (int nt = 0; nt < 8; ++nt) acc[nt] = zero4;
  #pragma unroll
  for (int nt = 0; nt < 8; ++nt) {
    acc[nt] = __builtin_amdgcn_mfma_f32_16x16x32_bf16(ua0.v, f1[(nt*2 + 0)*64 + l], acc[nt], 0, 0, 0);
    acc[nt] = __builtin_amdgcn_mfma_f32_16x16x32_bf16(ua1.v, f1[(nt*2 + 1)*64 + l], acc[nt], 0, 0, 0);
  }
  {
    const float* spC = (const float*)(wsb + O_SPC);
    const float* spB = (const float*)(wsb + O_SPB);
    #pragma unroll
    for (int nt = 0; nt < 8; ++nt) {
      float Cv = spC[nt*16 + lr], Bv = spB[nt*16 + lr];
      #pragma unroll
      for (int i = 0; i < 4; ++i) {
        float hv = rr[i]*(acc[nt][i] - mr[i]*Cv) + Bv;
        hw[(lq*4 + i)*136 + nt*16 + lr] = f2b(geluf(hv));
      }
    }
  }
  f32x4 a2[4];
  #pragma unroll
  for (int nt = 0; nt < 4; ++nt) a2[nt] = zero4;
  #pragma unroll
  for (int ks = 0; ks < 4; ++ks) {
    bf16x8 a = *(const bf16x8*)(hw + lr*136 + ks*32 + lq*8);
    #pragma unroll
    for (int nt = 0; nt < 4; ++nt)
      a2[nt] = __builtin_amdgcn_mfma_f32_16x16x32_bf16(a, f2[(nt*4 + ks)*64 + l], a2[nt], 0, 0, 0);
  }
  float ss[4] = {0.f,0.f,0.f,0.f}, qq[4] = {0.f,0.f,0.f,0.f};
  {
    unsigned short* s64p = (unsigned short*)(wsb + O_S64);
    #pragma unroll
    for (int nt = 0; nt < 4; ++nt) {
      float bv = sp2_b[nt*16 + lr];
      #pragma unroll
      for (int i = 0; i < 4; ++i) {
        unsigned short rb = f2b(a2[nt][i] + bv);
        s64p[(size_t)(srow + lq*4 + i)*64 + nt*16 + lr] = rb;
        float f = b2f(rb);
        ss[i] += f; qq[i] = fmaf(f, f, qq[i]);
      }
    }
  }
  #pragma unroll
  for (int i = 0; i < 4; ++i) {
    ss[i] += __shfl_xor(ss[i], 1, 64); ss[i] += __shfl_xor(ss[i], 2, 64);
    ss[i] += __shfl_xor(ss[i], 4, 64); ss[i] += __shfl_xor(ss[i], 8, 64);
    qq[i] += __shfl_xor(qq[i], 1, 64); qq[i] += __shfl_xor(qq[i], 2, 64);
    qq[i] += __shfl_xor(qq[i], 4, 64); qq[i] += __shfl_xor(qq[i], 8, 64);
  }
  if (lr == 0) {
    float* stat = (float*)(wsb + O_STAT);
    #pragma unroll
    for (int i = 0; i < 4; ++i) {
      size_t r = (size_t)srow + lq*4 + i;
      float2 fs = *(float2*)(stat + r*2);
      float stot = fs.x + ss[i], qtot = fs.y + qq[i];
      float m = stot*(1.f/352.f);
      float var = qtot*(1.f/352.f) - m*m;
      float2 o; o.x = m; o.y = rsqrtf(var + 1e-5f);
      *(float2*)(stat + r*2) = o;
    }
  }
}

// =================== K2b: heads, weights resident in LDS ===================
__global__ __launch_bounds__(512, 2) void k2b_heads(
    const float* __restrict__ hm2_b, const float* __restrict__ hq2_b,
    const float* __restrict__ hn2_b, const char* __restrict__ wsb,
    const unsigned short* __restrict__ feat, float* __restrict__ out)
{
  extern __shared__ char smem[];
  const int g = blockIdx.y;
  const int tid = threadIdx.x;
  const int wv = tid >> 6, l = tid & 63, lr = l & 15, lq = l >> 4;
  const int ntn = (g == 2) ? 6 : 12;
  {
    const uint4* src = (const uint4*)(wsb + O_HDFR + (size_t)g*135168);
    uint4* dst = (uint4*)smem;
    const int n = ntn*11*64;
    for (int o = tid; o < n; o += 512) dst[o] = src[o];
  }
  __syncthreads();
  const bf16x8* wfr = (const bf16x8*)smem;
  const float* hdC = (const float*)(wsb + O_HDC);
  const float* hdB = (const float*)(wsb + O_HDBP);
  const float* w2c = (const float*)(wsb + O_W2C);
  const float* stat = (const float*)(wsb + O_STAT);
  const float* baseb = (const float*)(wsb + O_BASE);
  const unsigned short* s64p = (const unsigned short*)(wsb + O_S64);
  const float hb = (g == 0) ? hm2_b[0] : (g == 1) ? hq2_b[0] : hn2_b[0];
  const f32x4 zero4 = {0.f, 0.f, 0.f, 0.f};

  for (int c = blockIdx.x; c < 256; c += gridDim.x) {
    const int base = c*256 + wv*32;
    bf16x8 afr0[11], afr1[11];
    {
      const unsigned short* fr0 = feat + (size_t)(base + lr)*288;
      const unsigned short* fr1 = feat + (size_t)(base + 16 + lr)*288;
      #pragma unroll
      for (int ks = 0; ks < 9; ++ks) {
        afr0[ks] = *(const bf16x8*)(fr0 + ks*32 + lq*8);
        afr1[ks] = *(const bf16x8*)(fr1 + ks*32 + lq*8);
      }
      const unsigned short* sr0 = s64p + (size_t)(base + lr)*64;
      const unsigned short* sr1 = s64p + (size_t)(base + 16 + lr)*64;
      afr0[9]  = *(const bf16x8*)(sr0 + lq*8);
      afr0[10] = *(const bf16x8*)(sr0 + 32 + lq*8);
      afr1[9]  = *(const bf16x8*)(sr1 + lq*8);
      afr1[10] = *(const bf16x8*)(sr1 + 32 + lq*8);
    }
    float mr0[4], rr0[4], mr1[4], rr1[4];
    #pragma unroll
    for (int i = 0; i < 4; ++i) {
      float2 s0 = *(const float2*)(stat + (size_t)(base + lq*4 + i)*2);
      float2 s1 = *(const float2*)(stat + (size_t)(base + 16 + lq*4 + i)*2);
      mr0[i] = s0.x; rr0[i] = s0.y; mr1[i] = s1.x; rr1[i] = s1.y;
    }
    float pr0[4] = {0.f,0.f,0.f,0.f}, pr1[4] = {0.f,0.f,0.f,0.f};
    for (int nt = 0; nt < ntn; ++nt) {
      const int col = (g*12 + nt)*16 + lr;
      const float Cv = hdC[col], Bv = hdB[col], w2v = w2c[col];
      f32x4 a0 = zero4, a1v = zero4;
      #pragma unroll
      for (int ks = 0; ks < 11; ++ks) {
        bf16x8 b = wfr[(nt*11 + ks)*64 + l];
        a0  = __builtin_amdgcn_mfma_f32_16x16x32_bf16(afr0[ks], b, a0, 0, 0, 0);
        a1v = __builtin_amdgcn_mfma_f32_16x16x32_bf16(afr1[ks], b, a1v, 0, 0, 0);
      }
      #pragma unroll
      for (int i = 0; i < 4; ++i) {
        pr0[i] += geluf(rr0[i]*(a0[i]  - mr0[i]*Cv) + Bv) * w2v;
        pr1[i] += geluf(rr1[i]*(a1v[i] - mr1[i]*Cv) + Bv) * w2v;
      }
    }
    #pragma unroll
    for (int i = 0; i < 4; ++i) {
      float v0 = pr0[i], v1 = pr1[i];
      v0 += __shfl_xor(v0, 1, 64); v0 += __shfl_xor(v0, 2, 64);
      v0 += __shfl_xor(v0, 4, 64); v0 += __shfl_xor(v0, 8, 64);
      v1 += __shfl_xor(v1, 1, 64); v1 += __shfl_xor(v1, 2, 64);
      v1 += __shfl_xor(v1, 4, 64); v1 += __shfl_xor(v1, 8, 64);
      if (lr == 0) {
        int r0 = base + lq*4 + i;
        int r1 = base + 16 + lq*4 + i;
        float b0 = (g < 2) ? baseb[r0] : 0.f;
        float b1 = (g < 2) ? baseb[r1] : 0.f;
        out[(size_t)g*NB + r0] = b0 + hb + v0;
        out[(size_t)g*NB + r1] = b1 + hb + v1;
      }
    }
  }
}

extern "C" void kernel_launch(void* const* d_in, const int* in_sizes, int n_in,
                              void* d_out, int out_size, void* d_ws, size_t ws_size,
                              hipStream_t stream) {
  (void)in_sizes; (void)n_in; (void)out_size; (void)ws_size;
  const float* x_num    = (const float*)d_in[0];
  const float* x_static = (const float*)d_in[1];
  const int*   x_cat    = (const int*)  d_in[2];
  const float* cat_emb  = (const float*)d_in[3];
  const float* day_emb  = (const float*)d_in[4];
  const float* xproj_w  = (const float*)d_in[5];
  const float* xproj_b  = (const float*)d_in[6];
  const float* h0       = (const float*)d_in[7];
  const float* bln_g    = (const float*)d_in[8];
  const float* bln_b    = (const float*)d_in[9];
  const float* fc1_w    = (const float*)d_in[10];
  const float* fc1_b    = (const float*)d_in[11];
  const float* fc2_w    = (const float*)d_in[12];
  const float* fc2_b    = (const float*)d_in[13];
  const float* spln_g   = (const float*)d_in[14];
  const float* spln_b   = (const float*)d_in[15];
  const float* sp1_w    = (const float*)d_in[16];
  const float* sp1_b    = (const float*)d_in[17];
  const float* sp2_w    = (const float*)d_in[18];
  const float* sp2_b    = (const float*)d_in[19];
  const float* base_w   = (const float*)d_in[20];
  const float* base_b   = (const float*)d_in[21];
  const float* hln_g    = (const float*)d_in[22];
  const float* hln_b    = (const float*)d_in[23];
  const float* hm1_w    = (const float*)d_in[24];
  const float* hm1_b    = (const float*)d_in[25];
  const float* hm2_w    = (const float*)d_in[26];
  const float* hm2_b    = (const float*)d_in[27];
  const float* hq1_w    = (const float*)d_in[28];
  const float* hq1_b    = (const float*)d_in[29];
  const float* hq2_w    = (const float*)d_in[30];
  const float* hq2_b    = (const float*)d_in[31];
  const float* hn1_w    = (const float*)d_in[32];
  const float* hn1_b    = (const float*)d_in[33];
  const float* hn2_w    = (const float*)d_in[34];
  const float* hn2_b    = (const float*)d_in[35];

  char* wsb = (char*)d_ws;
  unsigned short* feat = (unsigned short*)(wsb + O_FEAT);
  unsigned short* xrow = (unsigned short*)(wsb + O_XROW);
  float* xstat = (float*)(wsb + O_XSTAT);
  float* statg = (float*)(wsb + O_STAT);
  float* out = (float*)d_out;

  k0_pre<<<586, 512, 0, stream>>>(cat_emb, day_emb, xproj_w, xproj_b,
      bln_g, bln_b, fc1_w, fc1_b, fc2_w, spln_g, spln_b, sp1_w, sp1_b, sp2_w,
      hln_g, hln_b, hm1_w, hm1_b, hq1_w, hq1_b, hn1_w, hn1_b,
      hm2_w, hq2_w, hn2_w, wsb);
  k1a_xproj<<<7168, 256, 0, stream>>>(x_num, x_cat, wsb, xrow, xstat);
  k1_scan<<<512, 512, 161792, stream>>>(h0, fc2_b, wsb, xrow, xstat, feat, statg);
  k1b_static<<<512, 512, 0, stream>>>(x_static, sp2_b, base_w, base_b, wsb);
  k2b_heads<<<dim3(86, 3), 512, 135168, stream>>>(hm2_b, hq2_b, hn2_b,
      wsb, feat, out);
}